// Round 9
// baseline (662.765 us; speedup 1.0000x reference)
//
#include <hip/hip_runtime.h>

// Problem constants (fixed by the reference)
constexpr int B_  = 4;
constexpr int N_  = 2048;
constexpr int HID_ = 1024;
constexpr int NH_ = 4;
constexpr int DK_ = 256;
constexpr int DV_ = 512;
constexpr int C_  = 64;     // chunk size
constexpr int NC_ = 32;     // chunks per sequence
constexpr int M_  = B_ * N_;  // 8192 rows
constexpr int NSEG_ = 4;    // scan segments
constexpr int CSEG_ = NC_ / NSEG_;  // 8 chunks per segment

using ushort_t = unsigned short;
typedef __attribute__((ext_vector_type(8))) short bf16x8;
typedef __attribute__((ext_vector_type(4))) float f32x4;

__device__ __forceinline__ ushort_t f2bf(float f) {
  union { float fv; unsigned u; } v; v.fv = f;
  unsigned r = v.u + 0x7FFFu + ((v.u >> 16) & 1u);   // round-to-nearest-even
  return (ushort_t)(r >> 16);
}
__device__ __forceinline__ float bf2f(ushort_t u) {
  union { unsigned u; float f; } v; v.u = ((unsigned)u) << 16; return v.f;
}

__device__ __forceinline__ void gload_lds16(const void* g, void* l) {
  __builtin_amdgcn_global_load_lds(
      (const __attribute__((address_space(1))) unsigned int*)g,
      (__attribute__((address_space(3))) unsigned int*)l, 16, 0, 0);
}

__device__ __forceinline__ f32x4 mfma16(bf16x8 a, bf16x8 b, f32x4 c) {
  return __builtin_amdgcn_mfma_f32_16x16x32_bf16(a, b, c, 0, 0, 0);
}

// ---------------------------------------------------------------------------
// bf16 MFMA GEMM: C[M,N] = A[M,K] bf16 @ BT[N,K] bf16.  Out fp32 or bf16.
// 128x128 tile, BK=32, 256 thr = 4 waves, m97 2-barrier loop.
// ---------------------------------------------------------------------------
template<bool BF16OUT>
__global__ __launch_bounds__(256) void gemm_mfma(
    const ushort_t* __restrict__ A, const ushort_t* __restrict__ BT,
    void* __restrict__ CV, int N, int K) {
  __shared__ ushort_t Asl[128 * 32];
  __shared__ ushort_t Bsl[128 * 32];
  const int tid = threadIdx.x;
  const int wave = tid >> 6, lane = tid & 63;
  const size_t brow = (size_t)blockIdx.y * 128;
  const size_t bcol = (size_t)blockIdx.x * 128;
  const int wr = (wave >> 1) * 64, wc = (wave & 1) * 64;

  f32x4 acc[4][4];
#pragma unroll
  for (int m = 0; m < 4; ++m)
#pragma unroll
    for (int n = 0; n < 4; ++n) acc[m][n] = f32x4{0.f, 0.f, 0.f, 0.f};

  const int kk   = (lane & 3) * 8;     // staging k within tile
  const int frow = lane & 15;          // fragment row/col
  const int fk   = (lane >> 4) * 8;    // fragment k-slice

  for (int k0 = 0; k0 < K; k0 += 32) {
#pragma unroll
    for (int j = 0; j < 2; ++j) {
      const int cbase = j * 4 + wave;                 // 0..7 (wave-uniform)
      const int row   = (cbase * 64 + lane) >> 2;     // 0..127
      gload_lds16(A  + (brow + row) * K + k0 + kk, Asl + cbase * 512);
      gload_lds16(BT + (bcol + row) * K + k0 + kk, Bsl + cbase * 512);
    }
    __syncthreads();

    bf16x8 af[4], bfr[4];
#pragma unroll
    for (int m = 0; m < 4; ++m)
      af[m] = *(const bf16x8*)(Asl + (wr + m * 16 + frow) * 32 + fk);
#pragma unroll
    for (int n = 0; n < 4; ++n)
      bfr[n] = *(const bf16x8*)(Bsl + (wc + n * 16 + frow) * 32 + fk);
#pragma unroll
    for (int m = 0; m < 4; ++m)
#pragma unroll
      for (int n = 0; n < 4; ++n)
        acc[m][n] = mfma16(af[m], bfr[n], acc[m][n]);
    __syncthreads();
  }

  const int crow = (lane >> 4) * 4;
  const int ccol = lane & 15;
#pragma unroll
  for (int m = 0; m < 4; ++m)
#pragma unroll
    for (int n = 0; n < 4; ++n) {
      const size_t base = (brow + wr + m * 16 + crow) * (size_t)N + (bcol + wc + n * 16 + ccol);
      if constexpr (BF16OUT) {
        ushort_t* Out = (ushort_t*)CV;
#pragma unroll
        for (int j = 0; j < 4; ++j) Out[base + (size_t)j * N] = f2bf(acc[m][n][j]);
      } else {
        float* Out = (float*)CV;
#pragma unroll
        for (int j = 0; j < 4; ++j) Out[base + (size_t)j * N] = acc[m][n][j];
      }
    }
}

// ---------------------------------------------------------------------------
// fp32 -> bf16 elementwise (4 elems/thread)
// ---------------------------------------------------------------------------
__global__ __launch_bounds__(256) void conv_to_bf16(const float* __restrict__ in,
    ushort_t* __restrict__ out) {
  const size_t i = ((size_t)blockIdx.x * 256 + threadIdx.x) * 4;
  float4 v = *(const float4*)(in + i);
  ushort4 r;
  r.x = f2bf(v.x); r.y = f2bf(v.y); r.z = f2bf(v.z); r.w = f2bf(v.w);
  *(ushort4*)(out + i) = r;
}

// ---------------------------------------------------------------------------
// W[K,N] fp32 -> WT[N,K] bf16 (tiled transpose)
// ---------------------------------------------------------------------------
__global__ __launch_bounds__(256) void transp_bf16(const float* __restrict__ W,
    ushort_t* __restrict__ WT, int K, int N) {
  __shared__ float tile[32][33];
  const int n0 = blockIdx.x * 32, k0 = blockIdx.y * 32;
  const int tx = threadIdx.x & 31, ty = threadIdx.x >> 5;
#pragma unroll
  for (int i = 0; i < 32; i += 8)
    tile[ty + i][tx] = W[(size_t)(k0 + ty + i) * N + n0 + tx];
  __syncthreads();
#pragma unroll
  for (int i = 0; i < 32; i += 8)
    WT[(size_t)(n0 + ty + i) * K + k0 + tx] = f2bf(tile[tx][ty + i]);
}

// ---------------------------------------------------------------------------
// gk[b,h,n] = logsigmoid(x[b,n,:]·Wgk[:,h] + bgk[h]) / 16
// ---------------------------------------------------------------------------
__global__ __launch_bounds__(256) void gk_kernel(const float* __restrict__ x,
    const float* __restrict__ Wgk, const float* __restrict__ bgk,
    float* __restrict__ gkbuf) {
  const int row  = blockIdx.x;
  const int b    = row / N_;
  const int n    = row - b * N_;
  const int tid  = threadIdx.x;
  const int wv   = tid >> 6;
  const int ln   = tid & 63;
  __shared__ float red2[256];
  const float* xr = x + (size_t)row * HID_;
  float s = 0.f;
  for (int i = ln; i < HID_; i += 64) s += xr[i] * Wgk[i * NH_ + wv];
  red2[tid] = s;
  __syncthreads();
  for (int off = 32; off; off >>= 1) {
    if (ln < off) red2[tid] += red2[tid + off];
    __syncthreads();
  }
  if (ln == 0) {
    float z  = red2[wv * 64] + bgk[wv];
    float ls = fminf(z, 0.f) - log1pf(expf(-fabsf(z)));
    gkbuf[((size_t)(b * NH_ + wv)) * N_ + n] = ls * (1.0f / 16.0f);
  }
}

// ---------------------------------------------------------------------------
// per-(bh,chunk) inclusive cumsum of gk
// ---------------------------------------------------------------------------
__global__ __launch_bounds__(64) void cumsum_kernel(const float* __restrict__ gkbuf,
                                                    float* __restrict__ gcbuf) {
  const int bh = blockIdx.x;
  const int c  = threadIdx.x;
  if (c < NC_) {
    const size_t base = (size_t)bh * N_ + c * C_;
    float acc = 0.f;
    for (int t = 0; t < C_; ++t) { acc += gkbuf[base + t]; gcbuf[base + t] = acc; }
  }
}

// ---------------------------------------------------------------------------
// A[bh,c,t,s] = (s<=t) ? (q_t·k_s)*(1/16)*exp(gc_t-gc_s) : 0  -> bf16
// ---------------------------------------------------------------------------
__global__ __launch_bounds__(256) void a_kernel(const float* __restrict__ q,
    const float* __restrict__ k, const float* __restrict__ gc,
    ushort_t* __restrict__ Abuf) {
  const int blk = blockIdx.x;
  const int bh  = blk >> 5, c = blk & 31;
  const int b   = bh >> 2, h = bh & 3;
  __shared__ float qs[64][68];
  __shared__ float ks_[64][68];
  __shared__ float gcs[64];
  const int tid = threadIdx.x;
  const int tx = tid & 15, ty = tid >> 4;
  const int lrow = tid >> 2;
  const int lc4  = (tid & 3) * 4;
  if (tid < 64) gcs[tid] = gc[(size_t)bh * N_ + c * C_ + tid];
  const float* qbase = q + (size_t)(b * N_ + c * C_) * (NH_ * DK_) + h * DK_;
  const float* kbase = k + (size_t)(b * N_ + c * C_) * (NH_ * DK_) + h * DK_;
  float acc[4][4] = {};
  for (int dt = 0; dt < 4; ++dt) {
    __syncthreads();
#pragma unroll
    for (int it = 0; it < 4; ++it) {
      int col = lc4 + it * 16;
      *(float4*)&qs[lrow][col]  = *(const float4*)(qbase + (size_t)lrow * (NH_ * DK_) + dt * 64 + col);
      *(float4*)&ks_[lrow][col] = *(const float4*)(kbase + (size_t)lrow * (NH_ * DK_) + dt * 64 + col);
    }
    __syncthreads();
    for (int i = 0; i < 4; ++i)
      for (int j = 0; j < 4; ++j) {
        const int t = ty * 4 + i, s = tx * 4 + j;
        float sm = 0.f;
        for (int d = 0; d < 64; ++d) sm += qs[t][d] * ks_[s][d];
        acc[i][j] += sm;
      }
  }
  ushort_t* ab = Abuf + (size_t)blk * 4096;
  const float scl = 0.0625f;
  for (int i = 0; i < 4; ++i) {
    const int t = ty * 4 + i;
    const float gct = gcs[t];
    ushort4 r;
    float v0 = (tx * 4 + 0 <= t) ? acc[i][0] * scl * expf(gct - gcs[tx * 4 + 0]) : 0.f;
    float v1 = (tx * 4 + 1 <= t) ? acc[i][1] * scl * expf(gct - gcs[tx * 4 + 1]) : 0.f;
    float v2 = (tx * 4 + 2 <= t) ? acc[i][2] * scl * expf(gct - gcs[tx * 4 + 2]) : 0.f;
    float v3 = (tx * 4 + 3 <= t) ? acc[i][3] * scl * expf(gct - gcs[tx * 4 + 3]) : 0.f;
    r.x = f2bf(v0); r.y = f2bf(v1); r.z = f2bf(v2); r.w = f2bf(v3);
    *(ushort4*)(ab + (size_t)t * 64 + tx * 4) = r;
  }
}

// ---------------------------------------------------------------------------
// q16[row][col] = bf16( q * (1/16) * e^gc )   (layout as q: [8192][1024])
// ---------------------------------------------------------------------------
__global__ __launch_bounds__(256) void pack_q16(const float* __restrict__ q,
    const float* __restrict__ gc, ushort_t* __restrict__ q16) {
  const size_t i4 = ((size_t)blockIdx.x * 256 + threadIdx.x) * 4;
  const int row = (int)(i4 >> 10);
  const int col = (int)(i4 & 1023);
  const int b = row >> 11, n = row & 2047;
  const int h = col >> 8;
  const float f = 0.0625f * expf(gc[(size_t)(b * NH_ + h) * N_ + n]);
  float4 v = *(const float4*)(q + i4);
  ushort4 r;
  r.x = f2bf(v.x * f); r.y = f2bf(v.y * f); r.z = f2bf(v.z * f); r.w = f2bf(v.w * f);
  *(ushort4*)(q16 + i4) = r;
}

// ---------------------------------------------------------------------------
// kT[bh][c][d 256][t 64] = bf16( k[t][d] * e^(gt - gc_t) )  — LDS transpose
// ---------------------------------------------------------------------------
__global__ __launch_bounds__(256) void pack_kT(const float* __restrict__ k,
    const float* __restrict__ gc, ushort_t* __restrict__ kT) {
  const int blk = blockIdx.x;
  const int bh = blk >> 5, c = blk & 31;
  const int b = bh >> 2, h = bh & 3;
  __shared__ ushort_t kl[256][68];
  __shared__ float fk[64];
  const int tid = threadIdx.x;
  if (tid < 64) {
    const float gct = gc[(size_t)bh * N_ + c * C_ + tid];
    const float gt  = gc[(size_t)bh * N_ + c * C_ + 63];
    fk[tid] = expf(gt - gct);
  }
  __syncthreads();
  const float* kb = k + (size_t)(b * N_ + c * C_) * 1024 + h * 256;
  for (int it = 0; it < 16; ++it) {
    const int e = it * 256 + tid;          // 4096 float4 slots
    const int t = e >> 6, d4 = (e & 63) * 4;
    float4 kv = *(const float4*)(kb + (size_t)t * 1024 + d4);
    const float f = fk[t];
    kl[d4 + 0][t] = f2bf(kv.x * f);
    kl[d4 + 1][t] = f2bf(kv.y * f);
    kl[d4 + 2][t] = f2bf(kv.z * f);
    kl[d4 + 3][t] = f2bf(kv.w * f);
  }
  __syncthreads();
  ushort_t* out = kT + (size_t)blk * 16384;
  for (int it = 0; it < 8; ++it) {
    const int e = it * 256 + tid;          // 2048 8B slots
    const int d = e >> 3, t8 = (e & 7) * 8;
    ushort4 lo, hi;
    lo.x = kl[d][t8 + 0]; lo.y = kl[d][t8 + 1]; lo.z = kl[d][t8 + 2]; lo.w = kl[d][t8 + 3];
    hi.x = kl[d][t8 + 4]; hi.y = kl[d][t8 + 5]; hi.z = kl[d][t8 + 6]; hi.w = kl[d][t8 + 7];
    *(ushort4*)(out + (size_t)d * 64 + t8)     = lo;
    *(ushort4*)(out + (size_t)d * 64 + t8 + 4) = hi;
  }
}

// ---------------------------------------------------------------------------
// vT[bh][e 512][n 2048] = v16[b, n, h*512+e]  — LDS transpose
// ---------------------------------------------------------------------------
__global__ __launch_bounds__(256) void pack_vT(const ushort_t* __restrict__ v16,
    ushort_t* __restrict__ vT) {
  const int blk = blockIdx.x;
  const int eh = blk & 1, c = (blk >> 1) & 31, bh = blk >> 6;
  const int b = bh >> 2, h = bh & 3;
  __shared__ ushort_t vl[256][68];
  const int tid = threadIdx.x;
  const ushort_t* vb = v16 + (size_t)(b * N_ + c * C_) * 2048 + h * 512 + eh * 256;
  for (int it = 0; it < 8; ++it) {
    const int e = it * 256 + tid;          // 2048 16B slots (64 s x 32 per row)
    const int s = e >> 5, c8 = (e & 31) * 8;
    bf16x8 val = *(const bf16x8*)(vb + (size_t)s * 2048 + c8);
#pragma unroll
    for (int j = 0; j < 8; ++j) vl[c8 + j][s] = (ushort_t)val[j];
  }
  __syncthreads();
  ushort_t* out = vT + (size_t)bh * 512 * 2048 + (size_t)(eh * 256) * 2048 + c * C_;
  for (int it = 0; it < 8; ++it) {
    const int e = it * 256 + tid;          // 2048 8B slots
    const int r = e >> 3, t8 = (e & 7) * 8;
    ushort4 lo, hi;
    lo.x = vl[r][t8 + 0]; lo.y = vl[r][t8 + 1]; lo.z = vl[r][t8 + 2]; lo.w = vl[r][t8 + 3];
    hi.x = vl[r][t8 + 4]; hi.y = vl[r][t8 + 5]; hi.z = vl[r][t8 + 6]; hi.w = vl[r][t8 + 7];
    *(ushort4*)(out + (size_t)r * 2048 + t8)     = lo;
    *(ushort4*)(out + (size_t)r * 2048 + t8 + 4) = hi;
  }
}

// ---------------------------------------------------------------------------
// Segmented MFMA chunk scan.  grid = (16 bh, 32 vblk, 4 seg) -> wgid%8 = bh%8
// (XCD affinity preserved).  2048 WGs = 8 WG/CU.  Each WG scans its 8 chunks
// with S starting at ZERO, writes segment-final state U (fp32) for seg<3.
// Kernel B combines boundary states; kernel C adds the cross-segment term.
// ---------------------------------------------------------------------------
__global__ __launch_bounds__(256) void scan_mfma(
    const ushort_t* __restrict__ q16,   // [8192][1024] pre-scaled bf16
    const ushort_t* __restrict__ kT,    // [bh][c][256][64] decayed bf16
    const ushort_t* __restrict__ vT,    // [bh][512][2048] bf16
    const ushort_t* __restrict__ ab,    // [bh*32+c][64][64] bf16
    const float*    __restrict__ gc,
    ushort_t* __restrict__ o,           // [8192][2048] bf16 (intra-segment part)
    float*    __restrict__ U) {         // [bh][seg 0..2][256][512] fp32
  const int bh = blockIdx.x, vblk = blockIdx.y, sg = blockIdx.z;
  const int b = bh >> 2, h = bh & 3;
  const int e0 = vblk * 16;
  const int c0 = sg * CSEG_;
  __shared__ ushort_t sbt[2][16][264];  // S^T bf16 double buffer
  __shared__ float egts[NC_];
  const int tid = threadIdx.x;
  const int w = tid >> 6, l = tid & 63;
  const int frow = l & 15, fgrp = l >> 4;

  for (int i = tid; i < 2 * 16 * 264 / 2; i += 256) ((unsigned*)&sbt[0][0][0])[i] = 0u;
  if (tid < NC_) egts[tid] = expf(gc[(size_t)bh * N_ + tid * C_ + 63]);
  f32x4 s_acc[4];
#pragma unroll
  for (int sm = 0; sm < 4; ++sm) s_acc[sm] = f32x4{0.f, 0.f, 0.f, 0.f};
  __syncthreads();

  const ushort_t* qbase = q16 + (size_t)(b * N_) * 1024 + h * 256;
  const ushort_t* kbase = kT + (size_t)bh * NC_ * 16384;
  const ushort_t* vbase = vT + (size_t)bh * 512 * 2048 + (size_t)e0 * 2048;
  const ushort_t* abase = ab + (size_t)bh * NC_ * 4096;
  ushort_t*       obase = o + (size_t)(b * N_) * 2048 + h * 512 + e0;

  for (int c = c0; c < c0 + CSEG_; ++c) {
    const float egt = egts[c];
    const ushort_t (*srd)[264] = sbt[(c & 1) ^ 1];   // state after chunk c-1
    ushort_t (*swr)[264] = sbt[c & 1];               // state after chunk c

    // ---- issue all global fragment loads for this chunk
    bf16x8 bv[2], aa[2], aq[8], ak[2][4];
#pragma unroll
    for (int kt = 0; kt < 2; ++kt)
      bv[kt] = *(const bf16x8*)(vbase + (size_t)frow * 2048 + c * C_ + kt * 32 + fgrp * 8);
#pragma unroll
    for (int kt = 0; kt < 2; ++kt)
      aa[kt] = *(const bf16x8*)(abase + (size_t)c * 4096 + (w * 16 + frow) * 64 + kt * 32 + fgrp * 8);
#pragma unroll
    for (int kk = 0; kk < 8; ++kk)
      aq[kk] = *(const bf16x8*)(qbase + (size_t)(c * C_ + w * 16 + frow) * 1024 + kk * 32 + fgrp * 8);
#pragma unroll
    for (int kt = 0; kt < 2; ++kt)
#pragma unroll
      for (int sm = 0; sm < 4; ++sm)
        ak[kt][sm] = *(const bf16x8*)(kbase + (size_t)c * 16384 +
                                      (size_t)(w * 64 + sm * 16 + frow) * 64 + kt * 32 + fgrp * 8);

    // ---- o = A@v + q@Sb   (wave w: o rows w*16..+16, cols e0..e0+16)
    f32x4 oa = f32x4{0.f, 0.f, 0.f, 0.f};
#pragma unroll
    for (int kt = 0; kt < 2; ++kt) oa = mfma16(aa[kt], bv[kt], oa);
#pragma unroll
    for (int kk = 0; kk < 8; ++kk) {
      bf16x8 bs = *(const bf16x8*)(&srd[frow][kk * 32 + fgrp * 8]);
      oa = mfma16(aq[kk], bs, oa);
    }
#pragma unroll
    for (int j = 0; j < 4; ++j)
      obase[(size_t)(c * C_ + w * 16 + fgrp * 4 + j) * 2048 + frow] = f2bf(oa[j]);

    // ---- S = e^gt * S + kT @ v   (wave w: d rows w*64..+64)
#pragma unroll
    for (int sm = 0; sm < 4; ++sm)
#pragma unroll
      for (int j = 0; j < 4; ++j) s_acc[sm][j] *= egt;
#pragma unroll
    for (int kt = 0; kt < 2; ++kt)
#pragma unroll
      for (int sm = 0; sm < 4; ++sm)
        s_acc[sm] = mfma16(ak[kt][sm], bv[kt], s_acc[sm]);

    // ---- publish S^T bf16 into the write buffer
#pragma unroll
    for (int sm = 0; sm < 4; ++sm) {
      ushort4 pk;
      pk.x = f2bf(s_acc[sm][0]); pk.y = f2bf(s_acc[sm][1]);
      pk.z = f2bf(s_acc[sm][2]); pk.w = f2bf(s_acc[sm][3]);
      *(ushort4*)&swr[frow][w * 64 + sm * 16 + fgrp * 4] = pk;
    }
    __syncthreads();   // publishes visible; next chunk reads swr as srd
  }

  // ---- write segment-final state U (fp32) for segments 0..2
  if (sg < NSEG_ - 1) {
    float* ub = U + (size_t)(bh * (NSEG_ - 1) + sg) * 256 * 512;
#pragma unroll
    for (int sm = 0; sm < 4; ++sm)
#pragma unroll
      for (int j = 0; j < 4; ++j)
        ub[(size_t)(w * 64 + sm * 16 + fgrp * 4 + j) * 512 + e0 + frow] = s_acc[sm][j];
  }
}

// ---------------------------------------------------------------------------
// Combine boundary states: S_in(s+1) = E_s * S_in(s) + U_s, store S_in^T bf16
// in B-fragment layout [bh][s 0..2][vblk][16 e][256 d].  grid (16, 32), 256 thr.
// ---------------------------------------------------------------------------
__global__ __launch_bounds__(256) void combine_kernel(const float* __restrict__ U,
    const float* __restrict__ gc, ushort_t* __restrict__ SinT) {
  const int bh = blockIdx.x, vb = blockIdx.y;
  const int d = threadIdx.x;            // 0..255
  float S[16];
#pragma unroll
  for (int e = 0; e < 16; ++e) S[e] = 0.f;
  for (int s = 0; s < NSEG_ - 1; ++s) {
    float gsum = 0.f;
    for (int c = s * CSEG_; c < (s + 1) * CSEG_; ++c)
      gsum += gc[(size_t)bh * N_ + c * C_ + 63];
    const float E = expf(gsum);
    const float* u = U + (size_t)(bh * (NSEG_ - 1) + s) * 256 * 512 + (size_t)d * 512 + vb * 16;
    ushort_t* out = SinT + (size_t)((bh * (NSEG_ - 1) + s) * 32 + vb) * 4096;
#pragma unroll
    for (int e = 0; e < 16; ++e) {
      S[e] = E * S[e] + u[e];
      out[e * 256 + d] = f2bf(S[e]);
    }
  }
}

// ---------------------------------------------------------------------------
// Cross-segment correction: o[t] += D_c * (q16[t] @ S_in(seg)).
// grid (16 bh, 32 vblk, 3), seg = z+1.  256 thr = 4 waves.
// ---------------------------------------------------------------------------
__global__ __launch_bounds__(256) void correct_kernel(
    const ushort_t* __restrict__ q16, const ushort_t* __restrict__ SinT,
    const float* __restrict__ gc, ushort_t* __restrict__ o) {
  const int bh = blockIdx.x, vb = blockIdx.y, z = blockIdx.z;
  const int sg = z + 1, c0 = sg * CSEG_;
  const int b = bh >> 2, h = bh & 3;
  __shared__ ushort_t sT[16][264];
  __shared__ float dseg[CSEG_];
  const int tid = threadIdx.x;
  const int w = tid >> 6, l = tid & 63;
  const int frow = l & 15, fgrp = l >> 4;

  {  // stage S_in^T slice: thread t covers e = t>>4, d = (t&15)*16 .. +16
    const ushort_t* src = SinT + (size_t)((bh * (NSEG_ - 1) + z) * 32 + vb) * 4096;
    const int e = tid >> 4, dbase = (tid & 15) * 16;
    bf16x8 v0 = *(const bf16x8*)(src + e * 256 + dbase);
    bf16x8 v1 = *(const bf16x8*)(src + e * 256 + dbase + 8);
    *(bf16x8*)&sT[e][dbase]     = v0;
    *(bf16x8*)&sT[e][dbase + 8] = v1;
  }
  if (tid < CSEG_) {
    float s = 0.f;
    for (int i = 0; i < tid; ++i) s += gc[(size_t)bh * N_ + (c0 + i) * C_ + 63];
    dseg[tid] = expf(s);
  }
  __syncthreads();

  const ushort_t* qbase = q16 + (size_t)(b * N_) * 1024 + h * 256;
  ushort_t* obase = o + (size_t)(b * N_) * 2048 + h * 512 + vb * 16;

  for (int c = c0; c < c0 + CSEG_; ++c) {
    const float D = dseg[c - c0];
    f32x4 oa = f32x4{0.f, 0.f, 0.f, 0.f};
#pragma unroll
    for (int kk = 0; kk < 8; ++kk) {
      bf16x8 aq = *(const bf16x8*)(qbase + (size_t)(c * C_ + w * 16 + frow) * 1024 + kk * 32 + fgrp * 8);
      bf16x8 bs = *(const bf16x8*)(&sT[frow][kk * 32 + fgrp * 8]);
      oa = mfma16(aq, bs, oa);
    }
#pragma unroll
    for (int j = 0; j < 4; ++j) {
      const size_t idx = (size_t)(c * C_ + w * 16 + fgrp * 4 + j) * 2048 + frow;
      obase[idx] = f2bf(bf2f(obase[idx]) + D * oa[j]);
    }
  }
}

// ---------------------------------------------------------------------------
// ob(bf16) <- RMSNorm(o bf16)*gnorm_w * swish(g fp32)
// ---------------------------------------------------------------------------
__global__ __launch_bounds__(256) void normgate_kernel(const ushort_t* __restrict__ o,
    const float* __restrict__ g, const float* __restrict__ w,
    ushort_t* __restrict__ ob) {
  const int blk = blockIdx.x;
  const size_t base = (size_t)blk * DV_;
  const int tid = threadIdx.x;
  __shared__ float red2[256];
  const float v0 = bf2f(o[base + tid]), v1 = bf2f(o[base + tid + 256]);
  red2[tid] = v0 * v0 + v1 * v1;
  __syncthreads();
  for (int off = 128; off; off >>= 1) {
    if (tid < off) red2[tid] += red2[tid + off];
    __syncthreads();
  }
  const float rms = rsqrtf(red2[0] * (1.0f / 512.0f) + 1e-5f);
  const float g0 = g[base + tid], g1 = g[base + tid + 256];
  const float sw0 = g0 / (1.f + expf(-g0));
  const float sw1 = g1 / (1.f + expf(-g1));
  ob[base + tid]       = f2bf(v0 * rms * w[tid] * sw0);
  ob[base + tid + 256] = f2bf(v1 * rms * w[tid + 256] * sw1);
}

// ---------------------------------------------------------------------------
// Workspace (float units), total 59,834,368 fl = 228.25 MiB (R7-proven size):
//   gk 32K | gc 32K | q 8.39M | k 8.39M | v16 8.39M | o 8.39M | ab16 1.05M |
//   q16 4.19M | kTp 4.19M | vTp 8.39M | xb 4.19M | W*T 4.19M
// Aliases (time-disjoint):
//   U    (6.29M fp32) = q region      [q dead after pack_q16]
//   SinT (3.15M fl)   = k region      [k dead after pack_kT]
//   g    (16.78M fp32)= q+k region    [written after correct_kernel]
//   ob   (bf16)       = q16 region    [q16 dead after correct_kernel]
// ---------------------------------------------------------------------------
extern "C" void kernel_launch(void* const* d_in, const int* in_sizes, int n_in,
                              void* d_out, int out_size, void* d_ws, size_t ws_size,
                              hipStream_t stream) {
  (void)in_sizes; (void)n_in; (void)out_size; (void)ws_size;
  const float* x    = (const float*)d_in[0];
  const float* Wq   = (const float*)d_in[1];
  const float* Wk   = (const float*)d_in[2];
  const float* Wv   = (const float*)d_in[3];
  const float* Wg   = (const float*)d_in[4];
  const float* Wgk  = (const float*)d_in[5];
  const float* bgk  = (const float*)d_in[6];
  const float* Wo   = (const float*)d_in[7];
  const float* gw   = (const float*)d_in[8];

  float* ws = (float*)d_ws;
  size_t off = 0;
  float* gk = ws + off; off += (size_t)16 * N_;
  float* gc = ws + off; off += (size_t)16 * N_;
  float* q  = ws + off; off += (size_t)M_ * 1024;
  float* k  = ws + off; off += (size_t)M_ * 1024;
  ushort_t* v16 = (ushort_t*)(ws + off); off += (size_t)M_ * 2048 / 2;
  ushort_t* o   = (ushort_t*)(ws + off); off += (size_t)M_ * 2048 / 2;
  ushort_t* ab16= (ushort_t*)(ws + off); off += (size_t)16 * NC_ * 4096 / 2;
  ushort_t* q16 = (ushort_t*)(ws + off); off += (size_t)M_ * 1024 / 2;
  ushort_t* kTp = (ushort_t*)(ws + off); off += (size_t)16 * NC_ * 16384 / 2;
  ushort_t* vTp = (ushort_t*)(ws + off); off += (size_t)16 * 512 * 2048 / 2;
  ushort_t* xb  = (ushort_t*)(ws + off); off += (size_t)M_ * HID_ / 2;
  ushort_t* WqT = (ushort_t*)(ws + off); off += (size_t)1024 * 1024 / 2;
  ushort_t* WkT = (ushort_t*)(ws + off); off += (size_t)1024 * 1024 / 2;
  ushort_t* WvT = (ushort_t*)(ws + off); off += (size_t)2048 * 1024 / 2;
  ushort_t* WgT = (ushort_t*)(ws + off); off += (size_t)2048 * 1024 / 2;
  ushort_t* WoT = (ushort_t*)(ws + off); off += (size_t)1024 * 2048 / 2;
  // time-disjoint aliases (see table above)
  float*    U    = q;                          // 6.29M fl, fits q (8.39M)
  ushort_t* SinT = (ushort_t*)k;               // 3.15M fl, fits k (8.39M)
  float*    g    = q;                          // 16.78M fl over q+k
  ushort_t* ob   = q16;                        // over q16

  dim3 thr(256);
  conv_to_bf16<<<M_ * HID_ / 1024, thr, 0, stream>>>(x, xb);
  transp_bf16<<<dim3(32, 32), thr, 0, stream>>>(Wq, WqT, 1024, 1024);
  transp_bf16<<<dim3(32, 32), thr, 0, stream>>>(Wk, WkT, 1024, 1024);
  transp_bf16<<<dim3(64, 32), thr, 0, stream>>>(Wv, WvT, 1024, 2048);
  transp_bf16<<<dim3(64, 32), thr, 0, stream>>>(Wg, WgT, 1024, 2048);
  transp_bf16<<<dim3(32, 64), thr, 0, stream>>>(Wo, WoT, 2048, 1024);

  gemm_mfma<false><<<dim3(8, 64), thr, 0, stream>>>(xb, WqT, q, 1024, 1024);
  gemm_mfma<false><<<dim3(8, 64), thr, 0, stream>>>(xb, WkT, k, 1024, 1024);
  gk_kernel<<<M_, thr, 0, stream>>>(x, Wgk, bgk, gk);
  cumsum_kernel<<<16, 64, 0, stream>>>(gk, gc);
  a_kernel<<<16 * NC_, thr, 0, stream>>>(q, k, gc, ab16);
  pack_q16<<<M_ * 1024 / 1024, thr, 0, stream>>>(q, gc, q16);
  pack_kT<<<16 * NC_, thr, 0, stream>>>(k, gc, kTp);
  gemm_mfma<true><<<dim3(16, 64), thr, 0, stream>>>(xb, WvT, v16, 2048, 1024);
  pack_vT<<<16 * NC_ * 2, thr, 0, stream>>>(v16, vTp);
  scan_mfma<<<dim3(16, 32, NSEG_), thr, 0, stream>>>(q16, kTp, vTp, ab16, gc, o, U);
  combine_kernel<<<dim3(16, 32), thr, 0, stream>>>(U, gc, SinT);
  correct_kernel<<<dim3(16, 32, NSEG_ - 1), thr, 0, stream>>>(q16, SinT, gc, o);
  gemm_mfma<false><<<dim3(16, 64), thr, 0, stream>>>(xb, WgT, g, 2048, 1024);
  normgate_kernel<<<M_ * NH_, thr, 0, stream>>>(o, g, gw, ob);
  gemm_mfma<false><<<dim3(8, 64), thr, 0, stream>>>(ob, WoT, (float*)d_out, 1024, 2048);
}

// Round 10
// 595.589 us; speedup vs baseline: 1.1128x; 1.1128x over previous
//
#include <hip/hip_runtime.h>

// Problem constants (fixed by the reference)
constexpr int B_  = 4;
constexpr int N_  = 2048;
constexpr int HID_ = 1024;
constexpr int NH_ = 4;
constexpr int DK_ = 256;
constexpr int DV_ = 512;
constexpr int C_  = 64;     // chunk size
constexpr int NC_ = 32;     // chunks per sequence
constexpr int M_  = B_ * N_;  // 8192 rows
constexpr int NSEG_ = 4;    // scan segments
constexpr int CSEG_ = NC_ / NSEG_;  // 8 chunks per segment

using ushort_t = unsigned short;
typedef __attribute__((ext_vector_type(8))) short bf16x8;
typedef __attribute__((ext_vector_type(4))) float f32x4;

__device__ __forceinline__ ushort_t f2bf(float f) {
  union { float fv; unsigned u; } v; v.fv = f;
  unsigned r = v.u + 0x7FFFu + ((v.u >> 16) & 1u);   // round-to-nearest-even
  return (ushort_t)(r >> 16);
}
__device__ __forceinline__ float bf2f(ushort_t u) {
  union { unsigned u; float f; } v; v.u = ((unsigned)u) << 16; return v.f;
}

__device__ __forceinline__ void gload_lds16(const void* g, void* l) {
  __builtin_amdgcn_global_load_lds(
      (const __attribute__((address_space(1))) unsigned int*)g,
      (__attribute__((address_space(3))) unsigned int*)l, 16, 0, 0);
}

__device__ __forceinline__ f32x4 mfma16(bf16x8 a, bf16x8 b, f32x4 c) {
  return __builtin_amdgcn_mfma_f32_16x16x32_bf16(a, b, c, 0, 0, 0);
}

// ---------------------------------------------------------------------------
// bf16 MFMA GEMM: C[M,N] = A[M,K] bf16 @ BT[N,K] bf16.  Out fp32 or bf16.
// 128x128 tile, BK=32, 256 thr = 4 waves, m97 2-barrier loop.
// ---------------------------------------------------------------------------
template<bool BF16OUT>
__global__ __launch_bounds__(256) void gemm_mfma(
    const ushort_t* __restrict__ A, const ushort_t* __restrict__ BT,
    void* __restrict__ CV, int N, int K) {
  __shared__ ushort_t Asl[128 * 32];
  __shared__ ushort_t Bsl[128 * 32];
  const int tid = threadIdx.x;
  const int wave = tid >> 6, lane = tid & 63;
  const size_t brow = (size_t)blockIdx.y * 128;
  const size_t bcol = (size_t)blockIdx.x * 128;
  const int wr = (wave >> 1) * 64, wc = (wave & 1) * 64;

  f32x4 acc[4][4];
#pragma unroll
  for (int m = 0; m < 4; ++m)
#pragma unroll
    for (int n = 0; n < 4; ++n) acc[m][n] = f32x4{0.f, 0.f, 0.f, 0.f};

  const int kk   = (lane & 3) * 8;     // staging k within tile
  const int frow = lane & 15;          // fragment row/col
  const int fk   = (lane >> 4) * 8;    // fragment k-slice

  for (int k0 = 0; k0 < K; k0 += 32) {
#pragma unroll
    for (int j = 0; j < 2; ++j) {
      const int cbase = j * 4 + wave;                 // 0..7 (wave-uniform)
      const int row   = (cbase * 64 + lane) >> 2;     // 0..127
      gload_lds16(A  + (brow + row) * K + k0 + kk, Asl + cbase * 512);
      gload_lds16(BT + (bcol + row) * K + k0 + kk, Bsl + cbase * 512);
    }
    __syncthreads();

    bf16x8 af[4], bfr[4];
#pragma unroll
    for (int m = 0; m < 4; ++m)
      af[m] = *(const bf16x8*)(Asl + (wr + m * 16 + frow) * 32 + fk);
#pragma unroll
    for (int n = 0; n < 4; ++n)
      bfr[n] = *(const bf16x8*)(Bsl + (wc + n * 16 + frow) * 32 + fk);
#pragma unroll
    for (int m = 0; m < 4; ++m)
#pragma unroll
      for (int n = 0; n < 4; ++n)
        acc[m][n] = mfma16(af[m], bfr[n], acc[m][n]);
    __syncthreads();
  }

  const int crow = (lane >> 4) * 4;
  const int ccol = lane & 15;
#pragma unroll
  for (int m = 0; m < 4; ++m)
#pragma unroll
    for (int n = 0; n < 4; ++n) {
      const size_t base = (brow + wr + m * 16 + crow) * (size_t)N + (bcol + wc + n * 16 + ccol);
      if constexpr (BF16OUT) {
        ushort_t* Out = (ushort_t*)CV;
#pragma unroll
        for (int j = 0; j < 4; ++j) Out[base + (size_t)j * N] = f2bf(acc[m][n][j]);
      } else {
        float* Out = (float*)CV;
#pragma unroll
        for (int j = 0; j < 4; ++j) Out[base + (size_t)j * N] = acc[m][n][j];
      }
    }
}

// ---------------------------------------------------------------------------
// fp32 -> bf16 elementwise (4 elems/thread)
// ---------------------------------------------------------------------------
__global__ __launch_bounds__(256) void conv_to_bf16(const float* __restrict__ in,
    ushort_t* __restrict__ out) {
  const size_t i = ((size_t)blockIdx.x * 256 + threadIdx.x) * 4;
  float4 v = *(const float4*)(in + i);
  ushort4 r;
  r.x = f2bf(v.x); r.y = f2bf(v.y); r.z = f2bf(v.z); r.w = f2bf(v.w);
  *(ushort4*)(out + i) = r;
}

// ---------------------------------------------------------------------------
// W[K,N] fp32 -> WT[N,K] bf16 (tiled transpose)
// ---------------------------------------------------------------------------
__global__ __launch_bounds__(256) void transp_bf16(const float* __restrict__ W,
    ushort_t* __restrict__ WT, int K, int N) {
  __shared__ float tile[32][33];
  const int n0 = blockIdx.x * 32, k0 = blockIdx.y * 32;
  const int tx = threadIdx.x & 31, ty = threadIdx.x >> 5;
#pragma unroll
  for (int i = 0; i < 32; i += 8)
    tile[ty + i][tx] = W[(size_t)(k0 + ty + i) * N + n0 + tx];
  __syncthreads();
#pragma unroll
  for (int i = 0; i < 32; i += 8)
    WT[(size_t)(n0 + ty + i) * K + k0 + tx] = f2bf(tile[tx][ty + i]);
}

// ---------------------------------------------------------------------------
// gk[b,h,n] = logsigmoid(x[b,n,:]·Wgk[:,h] + bgk[h]) / 16
// ---------------------------------------------------------------------------
__global__ __launch_bounds__(256) void gk_kernel(const float* __restrict__ x,
    const float* __restrict__ Wgk, const float* __restrict__ bgk,
    float* __restrict__ gkbuf) {
  const int row  = blockIdx.x;
  const int b    = row / N_;
  const int n    = row - b * N_;
  const int tid  = threadIdx.x;
  const int wv   = tid >> 6;
  const int ln   = tid & 63;
  __shared__ float red2[256];
  const float* xr = x + (size_t)row * HID_;
  float s = 0.f;
  for (int i = ln; i < HID_; i += 64) s += xr[i] * Wgk[i * NH_ + wv];
  red2[tid] = s;
  __syncthreads();
  for (int off = 32; off; off >>= 1) {
    if (ln < off) red2[tid] += red2[tid + off];
    __syncthreads();
  }
  if (ln == 0) {
    float z  = red2[wv * 64] + bgk[wv];
    float ls = fminf(z, 0.f) - log1pf(expf(-fabsf(z)));
    gkbuf[((size_t)(b * NH_ + wv)) * N_ + n] = ls * (1.0f / 16.0f);
  }
}

// ---------------------------------------------------------------------------
// per-(bh,chunk) inclusive cumsum of gk
// ---------------------------------------------------------------------------
__global__ __launch_bounds__(64) void cumsum_kernel(const float* __restrict__ gkbuf,
                                                    float* __restrict__ gcbuf) {
  const int bh = blockIdx.x;
  const int c  = threadIdx.x;
  if (c < NC_) {
    const size_t base = (size_t)bh * N_ + c * C_;
    float acc = 0.f;
    for (int t = 0; t < C_; ++t) { acc += gkbuf[base + t]; gcbuf[base + t] = acc; }
  }
}

// ---------------------------------------------------------------------------
// A[bh,c,t,s] = (s<=t) ? (q_t·k_s)*(1/16)*exp(gc_t-gc_s) : 0  -> bf16
// ---------------------------------------------------------------------------
__global__ __launch_bounds__(256) void a_kernel(const float* __restrict__ q,
    const float* __restrict__ k, const float* __restrict__ gc,
    ushort_t* __restrict__ Abuf) {
  const int blk = blockIdx.x;
  const int bh  = blk >> 5, c = blk & 31;
  const int b   = bh >> 2, h = bh & 3;
  __shared__ float qs[64][68];
  __shared__ float ks_[64][68];
  __shared__ float gcs[64];
  const int tid = threadIdx.x;
  const int tx = tid & 15, ty = tid >> 4;
  const int lrow = tid >> 2;
  const int lc4  = (tid & 3) * 4;
  if (tid < 64) gcs[tid] = gc[(size_t)bh * N_ + c * C_ + tid];
  const float* qbase = q + (size_t)(b * N_ + c * C_) * (NH_ * DK_) + h * DK_;
  const float* kbase = k + (size_t)(b * N_ + c * C_) * (NH_ * DK_) + h * DK_;
  float acc[4][4] = {};
  for (int dt = 0; dt < 4; ++dt) {
    __syncthreads();
#pragma unroll
    for (int it = 0; it < 4; ++it) {
      int col = lc4 + it * 16;
      *(float4*)&qs[lrow][col]  = *(const float4*)(qbase + (size_t)lrow * (NH_ * DK_) + dt * 64 + col);
      *(float4*)&ks_[lrow][col] = *(const float4*)(kbase + (size_t)lrow * (NH_ * DK_) + dt * 64 + col);
    }
    __syncthreads();
    for (int i = 0; i < 4; ++i)
      for (int j = 0; j < 4; ++j) {
        const int t = ty * 4 + i, s = tx * 4 + j;
        float sm = 0.f;
        for (int d = 0; d < 64; ++d) sm += qs[t][d] * ks_[s][d];
        acc[i][j] += sm;
      }
  }
  ushort_t* ab = Abuf + (size_t)blk * 4096;
  const float scl = 0.0625f;
  for (int i = 0; i < 4; ++i) {
    const int t = ty * 4 + i;
    const float gct = gcs[t];
    ushort4 r;
    float v0 = (tx * 4 + 0 <= t) ? acc[i][0] * scl * expf(gct - gcs[tx * 4 + 0]) : 0.f;
    float v1 = (tx * 4 + 1 <= t) ? acc[i][1] * scl * expf(gct - gcs[tx * 4 + 1]) : 0.f;
    float v2 = (tx * 4 + 2 <= t) ? acc[i][2] * scl * expf(gct - gcs[tx * 4 + 2]) : 0.f;
    float v3 = (tx * 4 + 3 <= t) ? acc[i][3] * scl * expf(gct - gcs[tx * 4 + 3]) : 0.f;
    r.x = f2bf(v0); r.y = f2bf(v1); r.z = f2bf(v2); r.w = f2bf(v3);
    *(ushort4*)(ab + (size_t)t * 64 + tx * 4) = r;
  }
}

// ---------------------------------------------------------------------------
// q16[row][col] = bf16( q * (1/16) * e^gc )   (layout as q: [8192][1024])
// ---------------------------------------------------------------------------
__global__ __launch_bounds__(256) void pack_q16(const float* __restrict__ q,
    const float* __restrict__ gc, ushort_t* __restrict__ q16) {
  const size_t i4 = ((size_t)blockIdx.x * 256 + threadIdx.x) * 4;
  const int row = (int)(i4 >> 10);
  const int col = (int)(i4 & 1023);
  const int b = row >> 11, n = row & 2047;
  const int h = col >> 8;
  const float f = 0.0625f * expf(gc[(size_t)(b * NH_ + h) * N_ + n]);
  float4 v = *(const float4*)(q + i4);
  ushort4 r;
  r.x = f2bf(v.x * f); r.y = f2bf(v.y * f); r.z = f2bf(v.z * f); r.w = f2bf(v.w * f);
  *(ushort4*)(q16 + i4) = r;
}

// ---------------------------------------------------------------------------
// kT[bh][c][d 256][t 64] = bf16( k[t][d] * e^(gt - gc_t) )  — LDS transpose
// ---------------------------------------------------------------------------
__global__ __launch_bounds__(256) void pack_kT(const float* __restrict__ k,
    const float* __restrict__ gc, ushort_t* __restrict__ kT) {
  const int blk = blockIdx.x;
  const int bh = blk >> 5, c = blk & 31;
  const int b = bh >> 2, h = bh & 3;
  __shared__ ushort_t kl[256][68];
  __shared__ float fk[64];
  const int tid = threadIdx.x;
  if (tid < 64) {
    const float gct = gc[(size_t)bh * N_ + c * C_ + tid];
    const float gt  = gc[(size_t)bh * N_ + c * C_ + 63];
    fk[tid] = expf(gt - gct);
  }
  __syncthreads();
  const float* kb = k + (size_t)(b * N_ + c * C_) * 1024 + h * 256;
  for (int it = 0; it < 16; ++it) {
    const int e = it * 256 + tid;          // 4096 float4 slots
    const int t = e >> 6, d4 = (e & 63) * 4;
    float4 kv = *(const float4*)(kb + (size_t)t * 1024 + d4);
    const float f = fk[t];
    kl[d4 + 0][t] = f2bf(kv.x * f);
    kl[d4 + 1][t] = f2bf(kv.y * f);
    kl[d4 + 2][t] = f2bf(kv.z * f);
    kl[d4 + 3][t] = f2bf(kv.w * f);
  }
  __syncthreads();
  ushort_t* out = kT + (size_t)blk * 16384;
  for (int it = 0; it < 8; ++it) {
    const int e = it * 256 + tid;          // 2048 8B slots
    const int d = e >> 3, t8 = (e & 7) * 8;
    ushort4 lo, hi;
    lo.x = kl[d][t8 + 0]; lo.y = kl[d][t8 + 1]; lo.z = kl[d][t8 + 2]; lo.w = kl[d][t8 + 3];
    hi.x = kl[d][t8 + 4]; hi.y = kl[d][t8 + 5]; hi.z = kl[d][t8 + 6]; hi.w = kl[d][t8 + 7];
    *(ushort4*)(out + (size_t)d * 64 + t8)     = lo;
    *(ushort4*)(out + (size_t)d * 64 + t8 + 4) = hi;
  }
}

// ---------------------------------------------------------------------------
// vT[bh][e 512][n 2048] = v16[b, n, h*512+e]  — LDS transpose
// ---------------------------------------------------------------------------
__global__ __launch_bounds__(256) void pack_vT(const ushort_t* __restrict__ v16,
    ushort_t* __restrict__ vT) {
  const int blk = blockIdx.x;
  const int eh = blk & 1, c = (blk >> 1) & 31, bh = blk >> 6;
  const int b = bh >> 2, h = bh & 3;
  __shared__ ushort_t vl[256][68];
  const int tid = threadIdx.x;
  const ushort_t* vb = v16 + (size_t)(b * N_ + c * C_) * 2048 + h * 512 + eh * 256;
  for (int it = 0; it < 8; ++it) {
    const int e = it * 256 + tid;          // 2048 16B slots (64 s x 32 per row)
    const int s = e >> 5, c8 = (e & 31) * 8;
    bf16x8 val = *(const bf16x8*)(vb + (size_t)s * 2048 + c8);
#pragma unroll
    for (int j = 0; j < 8; ++j) vl[c8 + j][s] = (ushort_t)val[j];
  }
  __syncthreads();
  ushort_t* out = vT + (size_t)bh * 512 * 2048 + (size_t)(eh * 256) * 2048 + c * C_;
  for (int it = 0; it < 8; ++it) {
    const int e = it * 256 + tid;          // 2048 8B slots
    const int r = e >> 3, t8 = (e & 7) * 8;
    ushort4 lo, hi;
    lo.x = vl[r][t8 + 0]; lo.y = vl[r][t8 + 1]; lo.z = vl[r][t8 + 2]; lo.w = vl[r][t8 + 3];
    hi.x = vl[r][t8 + 4]; hi.y = vl[r][t8 + 5]; hi.z = vl[r][t8 + 6]; hi.w = vl[r][t8 + 7];
    *(ushort4*)(out + (size_t)r * 2048 + t8)     = lo;
    *(ushort4*)(out + (size_t)r * 2048 + t8 + 4) = hi;
  }
}

// ---------------------------------------------------------------------------
// Segmented MFMA chunk scan, EBLK=64.  grid = (16 bh, 8 vblk, 4 seg),
// wgid%8 = bh%8 (XCD affinity).  512 WGs = 2/CU.  Each WG owns 64 V-columns:
// shared aq/ak/aa loads amortized over 4 n-blocks (4x fewer L2 transactions
// per unit output than EBLK=16).  S[256 d][64 e] in fp32 frags s_acc[4][4].
// Per chunk (ONE barrier, double-buffered S^T in LDS, 2x33.8 KB).
// ---------------------------------------------------------------------------
__global__ __launch_bounds__(256) void scan_mfma(
    const ushort_t* __restrict__ q16,   // [8192][1024] pre-scaled bf16
    const ushort_t* __restrict__ kT,    // [bh][c][256][64] decayed bf16
    const ushort_t* __restrict__ vT,    // [bh][512][2048] bf16
    const ushort_t* __restrict__ ab,    // [bh*32+c][64][64] bf16
    const float*    __restrict__ gc,
    ushort_t* __restrict__ o,           // [8192][2048] bf16 (intra-segment part)
    float*    __restrict__ U) {         // [bh][seg 0..2][256][512] fp32
  const int bh = blockIdx.x, vblk = blockIdx.y, sg = blockIdx.z;
  const int b = bh >> 2, h = bh & 3;
  const int e0 = vblk * 64;
  const int c0 = sg * CSEG_;
  __shared__ ushort_t sbt[2][64][264];  // S^T bf16 double buffer (67.6 KB)
  __shared__ float egts[NC_];
  const int tid = threadIdx.x;
  const int w = tid >> 6, l = tid & 63;
  const int frow = l & 15, fgrp = l >> 4;

  for (int i = tid; i < 2 * 64 * 264 / 2; i += 256) ((unsigned*)&sbt[0][0][0])[i] = 0u;
  if (tid < NC_) egts[tid] = expf(gc[(size_t)bh * N_ + tid * C_ + 63]);
  f32x4 s_acc[4][4];
#pragma unroll
  for (int sm = 0; sm < 4; ++sm)
#pragma unroll
    for (int sn = 0; sn < 4; ++sn) s_acc[sm][sn] = f32x4{0.f, 0.f, 0.f, 0.f};
  __syncthreads();

  const ushort_t* qbase = q16 + (size_t)(b * N_) * 1024 + h * 256;
  const ushort_t* kbase = kT + (size_t)bh * NC_ * 16384;
  const ushort_t* vbase = vT + (size_t)bh * 512 * 2048 + (size_t)e0 * 2048;
  const ushort_t* abase = ab + (size_t)bh * NC_ * 4096;
  ushort_t*       obase = o + (size_t)(b * N_) * 2048 + h * 512 + e0;

  for (int c = c0; c < c0 + CSEG_; ++c) {
    const float egt = egts[c];
    const ushort_t (*srd)[264] = sbt[(c & 1) ^ 1];   // state after chunk c-1
    ushort_t (*swr)[264] = sbt[c & 1];               // state after chunk c

    // ---- shared operand loads for this chunk (amortized over 4 n-blocks)
    bf16x8 bv[2][4], aa[2], aq[8];
#pragma unroll
    for (int kt = 0; kt < 2; ++kt)
#pragma unroll
      for (int n = 0; n < 4; ++n)
        bv[kt][n] = *(const bf16x8*)(vbase + (size_t)(n * 16 + frow) * 2048 +
                                     c * C_ + kt * 32 + fgrp * 8);
#pragma unroll
    for (int kt = 0; kt < 2; ++kt)
      aa[kt] = *(const bf16x8*)(abase + (size_t)c * 4096 + (w * 16 + frow) * 64 + kt * 32 + fgrp * 8);
#pragma unroll
    for (int kk = 0; kk < 8; ++kk)
      aq[kk] = *(const bf16x8*)(qbase + (size_t)(c * C_ + w * 16 + frow) * 1024 + kk * 32 + fgrp * 8);

    // ---- o = A@v + q@Sb   (wave w: o rows w*16..+16, cols e0..e0+64)
#pragma unroll
    for (int n = 0; n < 4; ++n) {
      f32x4 oa = f32x4{0.f, 0.f, 0.f, 0.f};
#pragma unroll
      for (int kt = 0; kt < 2; ++kt) oa = mfma16(aa[kt], bv[kt][n], oa);
#pragma unroll
      for (int kk = 0; kk < 8; ++kk) {
        bf16x8 bs = *(const bf16x8*)(&srd[n * 16 + frow][kk * 32 + fgrp * 8]);
        oa = mfma16(aq[kk], bs, oa);
      }
#pragma unroll
      for (int j = 0; j < 4; ++j)
        obase[(size_t)(c * C_ + w * 16 + fgrp * 4 + j) * 2048 + n * 16 + frow] = f2bf(oa[j]);
    }

    // ---- S = e^gt * S + kT @ v   (wave w: d rows w*64..+64, all 64 e)
#pragma unroll
    for (int sm = 0; sm < 4; ++sm)
#pragma unroll
      for (int sn = 0; sn < 4; ++sn)
#pragma unroll
        for (int j = 0; j < 4; ++j) s_acc[sm][sn][j] *= egt;
#pragma unroll
    for (int kt = 0; kt < 2; ++kt)
#pragma unroll
      for (int sm = 0; sm < 4; ++sm) {
        bf16x8 ak = *(const bf16x8*)(kbase + (size_t)c * 16384 +
                                     (size_t)(w * 64 + sm * 16 + frow) * 64 + kt * 32 + fgrp * 8);
#pragma unroll
        for (int sn = 0; sn < 4; ++sn)
          s_acc[sm][sn] = mfma16(ak, bv[kt][sn], s_acc[sm][sn]);
      }

    // ---- publish S^T bf16 into the write buffer
#pragma unroll
    for (int sm = 0; sm < 4; ++sm)
#pragma unroll
      for (int sn = 0; sn < 4; ++sn) {
        ushort4 pk;
        pk.x = f2bf(s_acc[sm][sn][0]); pk.y = f2bf(s_acc[sm][sn][1]);
        pk.z = f2bf(s_acc[sm][sn][2]); pk.w = f2bf(s_acc[sm][sn][3]);
        *(ushort4*)&swr[sn * 16 + frow][w * 64 + sm * 16 + fgrp * 4] = pk;
      }
    __syncthreads();   // publishes visible; next chunk reads swr as srd
  }

  // ---- write segment-final state U (fp32) for segments 0..2
  if (sg < NSEG_ - 1) {
    float* ub = U + (size_t)(bh * (NSEG_ - 1) + sg) * 256 * 512;
#pragma unroll
    for (int sm = 0; sm < 4; ++sm)
#pragma unroll
      for (int sn = 0; sn < 4; ++sn)
#pragma unroll
        for (int j = 0; j < 4; ++j)
          ub[(size_t)(w * 64 + sm * 16 + fgrp * 4 + j) * 512 + e0 + sn * 16 + frow] =
              s_acc[sm][sn][j];
  }
}

// ---------------------------------------------------------------------------
// Combine boundary states: S_in(s+1) = E_s * S_in(s) + U_s, store S_in^T bf16
// in B-fragment layout [bh][s 0..2][vb of 16e][16 e][256 d].  grid (16, 32).
// ---------------------------------------------------------------------------
__global__ __launch_bounds__(256) void combine_kernel(const float* __restrict__ U,
    const float* __restrict__ gc, ushort_t* __restrict__ SinT) {
  const int bh = blockIdx.x, vb = blockIdx.y;
  const int d = threadIdx.x;            // 0..255
  float S[16];
#pragma unroll
  for (int e = 0; e < 16; ++e) S[e] = 0.f;
  for (int s = 0; s < NSEG_ - 1; ++s) {
    float gsum = 0.f;
    for (int c = s * CSEG_; c < (s + 1) * CSEG_; ++c)
      gsum += gc[(size_t)bh * N_ + c * C_ + 63];
    const float E = expf(gsum);
    const float* u = U + (size_t)(bh * (NSEG_ - 1) + s) * 256 * 512 + (size_t)d * 512 + vb * 16;
    ushort_t* out = SinT + (size_t)((bh * (NSEG_ - 1) + s) * 32 + vb) * 4096;
#pragma unroll
    for (int e = 0; e < 16; ++e) {
      S[e] = E * S[e] + u[e];
      out[e * 256 + d] = f2bf(S[e]);
    }
  }
}

// ---------------------------------------------------------------------------
// Cross-segment correction: o[t] += D_c * (q16[t] @ S_in(seg)).
// grid (16 bh, 32 vb, 3), seg = z+1.  256 thr = 4 waves.
// ---------------------------------------------------------------------------
__global__ __launch_bounds__(256) void correct_kernel(
    const ushort_t* __restrict__ q16, const ushort_t* __restrict__ SinT,
    const float* __restrict__ gc, ushort_t* __restrict__ o) {
  const int bh = blockIdx.x, vb = blockIdx.y, z = blockIdx.z;
  const int sg = z + 1, c0 = sg * CSEG_;
  const int b = bh >> 2, h = bh & 3;
  __shared__ ushort_t sT[16][264];
  __shared__ float dseg[CSEG_];
  const int tid = threadIdx.x;
  const int w = tid >> 6, l = tid & 63;
  const int frow = l & 15, fgrp = l >> 4;

  {  // stage S_in^T slice: thread t covers e = t>>4, d = (t&15)*16 .. +16
    const ushort_t* src = SinT + (size_t)((bh * (NSEG_ - 1) + z) * 32 + vb) * 4096;
    const int e = tid >> 4, dbase = (tid & 15) * 16;
    bf16x8 v0 = *(const bf16x8*)(src + e * 256 + dbase);
    bf16x8 v1 = *(const bf16x8*)(src + e * 256 + dbase + 8);
    *(bf16x8*)&sT[e][dbase]     = v0;
    *(bf16x8*)&sT[e][dbase + 8] = v1;
  }
  if (tid < CSEG_) {
    float s = 0.f;
    for (int i = 0; i < tid; ++i) s += gc[(size_t)bh * N_ + (c0 + i) * C_ + 63];
    dseg[tid] = expf(s);
  }
  __syncthreads();

  const ushort_t* qbase = q16 + (size_t)(b * N_) * 1024 + h * 256;
  ushort_t* obase = o + (size_t)(b * N_) * 2048 + h * 512 + vb * 16;

  for (int c = c0; c < c0 + CSEG_; ++c) {
    const float D = dseg[c - c0];
    f32x4 oa = f32x4{0.f, 0.f, 0.f, 0.f};
#pragma unroll
    for (int kk = 0; kk < 8; ++kk) {
      bf16x8 aq = *(const bf16x8*)(qbase + (size_t)(c * C_ + w * 16 + frow) * 1024 + kk * 32 + fgrp * 8);
      bf16x8 bs = *(const bf16x8*)(&sT[frow][kk * 32 + fgrp * 8]);
      oa = mfma16(aq, bs, oa);
    }
#pragma unroll
    for (int j = 0; j < 4; ++j) {
      const size_t idx = (size_t)(c * C_ + w * 16 + fgrp * 4 + j) * 2048 + frow;
      obase[idx] = f2bf(bf2f(obase[idx]) + D * oa[j]);
    }
  }
}

// ---------------------------------------------------------------------------
// ob(bf16) <- RMSNorm(o bf16)*gnorm_w * swish(g fp32)
// ---------------------------------------------------------------------------
__global__ __launch_bounds__(256) void normgate_kernel(const ushort_t* __restrict__ o,
    const float* __restrict__ g, const float* __restrict__ w,
    ushort_t* __restrict__ ob) {
  const int blk = blockIdx.x;
  const size_t base = (size_t)blk * DV_;
  const int tid = threadIdx.x;
  __shared__ float red2[256];
  const float v0 = bf2f(o[base + tid]), v1 = bf2f(o[base + tid + 256]);
  red2[tid] = v0 * v0 + v1 * v1;
  __syncthreads();
  for (int off = 128; off; off >>= 1) {
    if (tid < off) red2[tid] += red2[tid + off];
    __syncthreads();
  }
  const float rms = rsqrtf(red2[0] * (1.0f / 512.0f) + 1e-5f);
  const float g0 = g[base + tid], g1 = g[base + tid + 256];
  const float sw0 = g0 / (1.f + expf(-g0));
  const float sw1 = g1 / (1.f + expf(-g1));
  ob[base + tid]       = f2bf(v0 * rms * w[tid] * sw0);
  ob[base + tid + 256] = f2bf(v1 * rms * w[tid + 256] * sw1);
}

// ---------------------------------------------------------------------------
// Workspace (float units), total 59,834,368 fl = 228.25 MiB (R7/R9-proven):
//   gk 32K | gc 32K | q 8.39M | k 8.39M | v16 8.39M | o 8.39M | ab16 1.05M |
//   q16 4.19M | kTp 4.19M | vTp 8.39M | xb 4.19M | W*T 4.19M
// Aliases (time-disjoint):
//   U    (6.29M fp32) = q region      [q dead after pack_q16]
//   SinT (3.15M fl)   = k region      [k dead after pack_kT]
//   g    (16.78M fp32)= q+k region    [written after correct_kernel]
//   ob   (bf16)       = q16 region    [q16 dead after correct_kernel]
// ---------------------------------------------------------------------------
extern "C" void kernel_launch(void* const* d_in, const int* in_sizes, int n_in,
                              void* d_out, int out_size, void* d_ws, size_t ws_size,
                              hipStream_t stream) {
  (void)in_sizes; (void)n_in; (void)out_size; (void)ws_size;
  const float* x    = (const float*)d_in[0];
  const float* Wq   = (const float*)d_in[1];
  const float* Wk   = (const float*)d_in[2];
  const float* Wv   = (const float*)d_in[3];
  const float* Wg   = (const float*)d_in[4];
  const float* Wgk  = (const float*)d_in[5];
  const float* bgk  = (const float*)d_in[6];
  const float* Wo   = (const float*)d_in[7];
  const float* gw   = (const float*)d_in[8];

  float* ws = (float*)d_ws;
  size_t off = 0;
  float* gk = ws + off; off += (size_t)16 * N_;
  float* gc = ws + off; off += (size_t)16 * N_;
  float* q  = ws + off; off += (size_t)M_ * 1024;
  float* k  = ws + off; off += (size_t)M_ * 1024;
  ushort_t* v16 = (ushort_t*)(ws + off); off += (size_t)M_ * 2048 / 2;
  ushort_t* o   = (ushort_t*)(ws + off); off += (size_t)M_ * 2048 / 2;
  ushort_t* ab16= (ushort_t*)(ws + off); off += (size_t)16 * NC_ * 4096 / 2;
  ushort_t* q16 = (ushort_t*)(ws + off); off += (size_t)M_ * 1024 / 2;
  ushort_t* kTp = (ushort_t*)(ws + off); off += (size_t)16 * NC_ * 16384 / 2;
  ushort_t* vTp = (ushort_t*)(ws + off); off += (size_t)16 * 512 * 2048 / 2;
  ushort_t* xb  = (ushort_t*)(ws + off); off += (size_t)M_ * HID_ / 2;
  ushort_t* WqT = (ushort_t*)(ws + off); off += (size_t)1024 * 1024 / 2;
  ushort_t* WkT = (ushort_t*)(ws + off); off += (size_t)1024 * 1024 / 2;
  ushort_t* WvT = (ushort_t*)(ws + off); off += (size_t)2048 * 1024 / 2;
  ushort_t* WgT = (ushort_t*)(ws + off); off += (size_t)2048 * 1024 / 2;
  ushort_t* WoT = (ushort_t*)(ws + off); off += (size_t)1024 * 2048 / 2;
  // time-disjoint aliases (see table above)
  float*    U    = q;                          // 6.29M fl, fits q (8.39M)
  ushort_t* SinT = (ushort_t*)k;               // 3.15M fl, fits k (8.39M)
  float*    g    = q;                          // 16.78M fl over q+k
  ushort_t* ob   = q16;                        // over q16

  dim3 thr(256);
  conv_to_bf16<<<M_ * HID_ / 1024, thr, 0, stream>>>(x, xb);
  transp_bf16<<<dim3(32, 32), thr, 0, stream>>>(Wq, WqT, 1024, 1024);
  transp_bf16<<<dim3(32, 32), thr, 0, stream>>>(Wk, WkT, 1024, 1024);
  transp_bf16<<<dim3(64, 32), thr, 0, stream>>>(Wv, WvT, 1024, 2048);
  transp_bf16<<<dim3(64, 32), thr, 0, stream>>>(Wg, WgT, 1024, 2048);
  transp_bf16<<<dim3(32, 64), thr, 0, stream>>>(Wo, WoT, 2048, 1024);

  gemm_mfma<false><<<dim3(8, 64), thr, 0, stream>>>(xb, WqT, q, 1024, 1024);
  gemm_mfma<false><<<dim3(8, 64), thr, 0, stream>>>(xb, WkT, k, 1024, 1024);
  gk_kernel<<<M_, thr, 0, stream>>>(x, Wgk, bgk, gk);
  cumsum_kernel<<<16, 64, 0, stream>>>(gk, gc);
  a_kernel<<<16 * NC_, thr, 0, stream>>>(q, k, gc, ab16);
  pack_q16<<<M_ * 1024 / 1024, thr, 0, stream>>>(q, gc, q16);
  pack_kT<<<16 * NC_, thr, 0, stream>>>(k, gc, kTp);
  gemm_mfma<true><<<dim3(16, 64), thr, 0, stream>>>(xb, WvT, v16, 2048, 1024);
  pack_vT<<<16 * NC_ * 2, thr, 0, stream>>>(v16, vTp);
  scan_mfma<<<dim3(16, 8, NSEG_), thr, 0, stream>>>(q16, kTp, vTp, ab16, gc, o, U);
  combine_kernel<<<dim3(16, 32), thr, 0, stream>>>(U, gc, SinT);
  correct_kernel<<<dim3(16, 32, NSEG_ - 1), thr, 0, stream>>>(q16, SinT, gc, o);
  gemm_mfma<false><<<dim3(16, 64), thr, 0, stream>>>(xb, WgT, g, 2048, 1024);
  normgate_kernel<<<M_ * NH_, thr, 0, stream>>>(o, g, gw, ob);
  gemm_mfma<false><<<dim3(8, 64), thr, 0, stream>>>(ob, WoT, (float*)d_out, 1024, 2048);
}

// Round 11
// 522.072 us; speedup vs baseline: 1.2695x; 1.1408x over previous
//
#include <hip/hip_runtime.h>

// Problem constants (fixed by the reference)
constexpr int B_  = 4;
constexpr int N_  = 2048;
constexpr int HID_ = 1024;
constexpr int NH_ = 4;
constexpr int DK_ = 256;
constexpr int DV_ = 512;
constexpr int C_  = 64;     // chunk size
constexpr int NC_ = 32;     // chunks per sequence
constexpr int M_  = B_ * N_;  // 8192 rows
constexpr int NSEG_ = 4;    // scan segments
constexpr int CSEG_ = NC_ / NSEG_;  // 8 chunks per segment

using ushort_t = unsigned short;
typedef __attribute__((ext_vector_type(8))) short bf16x8;
typedef __attribute__((ext_vector_type(4))) float f32x4;

__device__ __forceinline__ ushort_t f2bf(float f) {
  union { float fv; unsigned u; } v; v.fv = f;
  unsigned r = v.u + 0x7FFFu + ((v.u >> 16) & 1u);   // round-to-nearest-even
  return (ushort_t)(r >> 16);
}
__device__ __forceinline__ float bf2f(ushort_t u) {
  union { unsigned u; float f; } v; v.u = ((unsigned)u) << 16; return v.f;
}

__device__ __forceinline__ void gload_lds16(const void* g, void* l) {
  __builtin_amdgcn_global_load_lds(
      (const __attribute__((address_space(1))) unsigned int*)g,
      (__attribute__((address_space(3))) unsigned int*)l, 16, 0, 0);
}

__device__ __forceinline__ f32x4 mfma16(bf16x8 a, bf16x8 b, f32x4 c) {
  return __builtin_amdgcn_mfma_f32_16x16x32_bf16(a, b, c, 0, 0, 0);
}

// ---------------------------------------------------------------------------
// bf16 MFMA GEMM: C[M,N] = A[M,K] bf16 @ BT[N,K] bf16.  Out fp32 or bf16.
// 128x128 tile, BK=32, 256 thr = 4 waves, m97 2-barrier loop.
// ---------------------------------------------------------------------------
template<bool BF16OUT>
__global__ __launch_bounds__(256) void gemm_mfma(
    const ushort_t* __restrict__ A, const ushort_t* __restrict__ BT,
    void* __restrict__ CV, int N, int K) {
  __shared__ ushort_t Asl[128 * 32];
  __shared__ ushort_t Bsl[128 * 32];
  const int tid = threadIdx.x;
  const int wave = tid >> 6, lane = tid & 63;
  const size_t brow = (size_t)blockIdx.y * 128;
  const size_t bcol = (size_t)blockIdx.x * 128;
  const int wr = (wave >> 1) * 64, wc = (wave & 1) * 64;

  f32x4 acc[4][4];
#pragma unroll
  for (int m = 0; m < 4; ++m)
#pragma unroll
    for (int n = 0; n < 4; ++n) acc[m][n] = f32x4{0.f, 0.f, 0.f, 0.f};

  const int kk   = (lane & 3) * 8;     // staging k within tile
  const int frow = lane & 15;          // fragment row/col
  const int fk   = (lane >> 4) * 8;    // fragment k-slice

  for (int k0 = 0; k0 < K; k0 += 32) {
#pragma unroll
    for (int j = 0; j < 2; ++j) {
      const int cbase = j * 4 + wave;                 // 0..7 (wave-uniform)
      const int row   = (cbase * 64 + lane) >> 2;     // 0..127
      gload_lds16(A  + (brow + row) * K + k0 + kk, Asl + cbase * 512);
      gload_lds16(BT + (bcol + row) * K + k0 + kk, Bsl + cbase * 512);
    }
    __syncthreads();

    bf16x8 af[4], bfr[4];
#pragma unroll
    for (int m = 0; m < 4; ++m)
      af[m] = *(const bf16x8*)(Asl + (wr + m * 16 + frow) * 32 + fk);
#pragma unroll
    for (int n = 0; n < 4; ++n)
      bfr[n] = *(const bf16x8*)(Bsl + (wc + n * 16 + frow) * 32 + fk);
#pragma unroll
    for (int m = 0; m < 4; ++m)
#pragma unroll
      for (int n = 0; n < 4; ++n)
        acc[m][n] = mfma16(af[m], bfr[n], acc[m][n]);
    __syncthreads();
  }

  const int crow = (lane >> 4) * 4;
  const int ccol = lane & 15;
#pragma unroll
  for (int m = 0; m < 4; ++m)
#pragma unroll
    for (int n = 0; n < 4; ++n) {
      const size_t base = (brow + wr + m * 16 + crow) * (size_t)N + (bcol + wc + n * 16 + ccol);
      if constexpr (BF16OUT) {
        ushort_t* Out = (ushort_t*)CV;
#pragma unroll
        for (int j = 0; j < 4; ++j) Out[base + (size_t)j * N] = f2bf(acc[m][n][j]);
      } else {
        float* Out = (float*)CV;
#pragma unroll
        for (int j = 0; j < 4; ++j) Out[base + (size_t)j * N] = acc[m][n][j];
      }
    }
}

// ---------------------------------------------------------------------------
// fp32 -> bf16 elementwise (4 elems/thread)
// ---------------------------------------------------------------------------
__global__ __launch_bounds__(256) void conv_to_bf16(const float* __restrict__ in,
    ushort_t* __restrict__ out) {
  const size_t i = ((size_t)blockIdx.x * 256 + threadIdx.x) * 4;
  float4 v = *(const float4*)(in + i);
  ushort4 r;
  r.x = f2bf(v.x); r.y = f2bf(v.y); r.z = f2bf(v.z); r.w = f2bf(v.w);
  *(ushort4*)(out + i) = r;
}

// ---------------------------------------------------------------------------
// W[K,N] fp32 -> WT[N,K] bf16 (tiled transpose)
// ---------------------------------------------------------------------------
__global__ __launch_bounds__(256) void transp_bf16(const float* __restrict__ W,
    ushort_t* __restrict__ WT, int K, int N) {
  __shared__ float tile[32][33];
  const int n0 = blockIdx.x * 32, k0 = blockIdx.y * 32;
  const int tx = threadIdx.x & 31, ty = threadIdx.x >> 5;
#pragma unroll
  for (int i = 0; i < 32; i += 8)
    tile[ty + i][tx] = W[(size_t)(k0 + ty + i) * N + n0 + tx];
  __syncthreads();
#pragma unroll
  for (int i = 0; i < 32; i += 8)
    WT[(size_t)(n0 + ty + i) * K + k0 + tx] = f2bf(tile[tx][ty + i]);
}

// ---------------------------------------------------------------------------
// gk[b,h,n] = logsigmoid(x[b,n,:]·Wgk[:,h] + bgk[h]) / 16
// ---------------------------------------------------------------------------
__global__ __launch_bounds__(256) void gk_kernel(const float* __restrict__ x,
    const float* __restrict__ Wgk, const float* __restrict__ bgk,
    float* __restrict__ gkbuf) {
  const int row  = blockIdx.x;
  const int b    = row / N_;
  const int n    = row - b * N_;
  const int tid  = threadIdx.x;
  const int wv   = tid >> 6;
  const int ln   = tid & 63;
  __shared__ float red2[256];
  const float* xr = x + (size_t)row * HID_;
  float s = 0.f;
  for (int i = ln; i < HID_; i += 64) s += xr[i] * Wgk[i * NH_ + wv];
  red2[tid] = s;
  __syncthreads();
  for (int off = 32; off; off >>= 1) {
    if (ln < off) red2[tid] += red2[tid + off];
    __syncthreads();
  }
  if (ln == 0) {
    float z  = red2[wv * 64] + bgk[wv];
    float ls = fminf(z, 0.f) - log1pf(expf(-fabsf(z)));
    gkbuf[((size_t)(b * NH_ + wv)) * N_ + n] = ls * (1.0f / 16.0f);
  }
}

// ---------------------------------------------------------------------------
// per-(bh,chunk) inclusive cumsum of gk
// ---------------------------------------------------------------------------
__global__ __launch_bounds__(64) void cumsum_kernel(const float* __restrict__ gkbuf,
                                                    float* __restrict__ gcbuf) {
  const int bh = blockIdx.x;
  const int c  = threadIdx.x;
  if (c < NC_) {
    const size_t base = (size_t)bh * N_ + c * C_;
    float acc = 0.f;
    for (int t = 0; t < C_; ++t) { acc += gkbuf[base + t]; gcbuf[base + t] = acc; }
  }
}

// ---------------------------------------------------------------------------
// MFMA A-matrix: A[bh,c,t,s] = (s<=t) ? (q_t·k_s)*(1/16)*exp(gc_t-gc_s) : 0
// q,k read as bf16 fragments from fused qk16 [8192][2048] (q cols 0..1023,
// k cols 1024..2047).  grid 512 (bh*32+c), 256 thr = 4 waves.
// Wave w computes A rows w*16..+16 (all 64 cols), 32 MFMAs.
// ---------------------------------------------------------------------------
__global__ __launch_bounds__(256) void a_mfma(const ushort_t* __restrict__ qk16,
    const float* __restrict__ gc, ushort_t* __restrict__ Abuf) {
  const int blk = blockIdx.x;
  const int bh  = blk >> 5, c = blk & 31;
  const int b   = bh >> 2, h = bh & 3;
  __shared__ float gcs[64];
  const int tid = threadIdx.x;
  const int w = tid >> 6, l = tid & 63;
  const int frow = l & 15, fgrp = l >> 4;
  if (tid < 64) gcs[tid] = gc[(size_t)bh * N_ + c * C_ + tid];
  __syncthreads();

  const size_t rbase = (size_t)(b * N_ + c * C_);
  // A-operand: q rows (this wave's m-tile), frag [m][k]
  bf16x8 aqr[8];
#pragma unroll
  for (int kk = 0; kk < 8; ++kk)
    aqr[kk] = *(const bf16x8*)(qk16 + (rbase + w * 16 + frow) * 2048 +
                               h * 256 + kk * 32 + fgrp * 8);

  ushort_t* ab = Abuf + (size_t)blk * 4096;
  const float scl = 0.0625f;
#pragma unroll
  for (int n = 0; n < 4; ++n) {
    f32x4 acc = f32x4{0.f, 0.f, 0.f, 0.f};
#pragma unroll
    for (int kk = 0; kk < 8; ++kk) {
      bf16x8 bk = *(const bf16x8*)(qk16 + (rbase + n * 16 + frow) * 2048 +
                                   1024 + h * 256 + kk * 32 + fgrp * 8);
      acc = mfma16(aqr[kk], bk, acc);
    }
    // C layout: col = lane&15 (s-local), row = fgrp*4+j (t-local)
    const int s = n * 16 + frow;
    const float gcss = gcs[s];
#pragma unroll
    for (int j = 0; j < 4; ++j) {
      const int t = w * 16 + fgrp * 4 + j;
      const float val = (s <= t) ? acc[j] * scl * expf(gcs[t] - gcss) : 0.f;
      ab[(size_t)t * 64 + s] = f2bf(val);
    }
  }
}

// ---------------------------------------------------------------------------
// q16[row][col] = bf16( q_raw(bf16) * (1/16) * e^gc ), q_raw from qk16 cols 0..1023
// ---------------------------------------------------------------------------
__global__ __launch_bounds__(256) void pack_q16(const ushort_t* __restrict__ qk16,
    const float* __restrict__ gc, ushort_t* __restrict__ q16) {
  const size_t i8 = ((size_t)blockIdx.x * 256 + threadIdx.x) * 8;   // < M*1024
  const int row = (int)(i8 >> 10);
  const int col = (int)(i8 & 1023);
  const int b = row >> 11, n = row & 2047;
  const int h = col >> 8;
  const float f = 0.0625f * expf(gc[(size_t)(b * NH_ + h) * N_ + n]);
  bf16x8 v = *(const bf16x8*)(qk16 + (size_t)row * 2048 + col);
  ushort_t r[8];
#pragma unroll
  for (int j = 0; j < 8; ++j) r[j] = f2bf(bf2f((ushort_t)v[j]) * f);
  *(bf16x8*)(q16 + i8) = *(bf16x8*)r;
}

// ---------------------------------------------------------------------------
// kT[bh][c][d 256][t 64] = bf16( k_raw(bf16) * e^(gt - gc_t) ) — LDS transpose
// k_raw from qk16 cols 1024..2047.
// ---------------------------------------------------------------------------
__global__ __launch_bounds__(256) void pack_kT(const ushort_t* __restrict__ qk16,
    const float* __restrict__ gc, ushort_t* __restrict__ kT) {
  const int blk = blockIdx.x;
  const int bh = blk >> 5, c = blk & 31;
  const int b = bh >> 2, h = bh & 3;
  __shared__ ushort_t kl[256][68];
  __shared__ float fk[64];
  const int tid = threadIdx.x;
  if (tid < 64) {
    const float gct = gc[(size_t)bh * N_ + c * C_ + tid];
    const float gt  = gc[(size_t)bh * N_ + c * C_ + 63];
    fk[tid] = expf(gt - gct);
  }
  __syncthreads();
  const ushort_t* kb = qk16 + (size_t)(b * N_ + c * C_) * 2048 + 1024 + h * 256;
  for (int it = 0; it < 8; ++it) {
    const int e = it * 256 + tid;          // 2048 8-elem slots
    const int t = e >> 5, d8 = (e & 31) * 8;
    bf16x8 kv = *(const bf16x8*)(kb + (size_t)t * 2048 + d8);
    const float f = fk[t];
#pragma unroll
    for (int j = 0; j < 8; ++j) kl[d8 + j][t] = f2bf(bf2f((ushort_t)kv[j]) * f);
  }
  __syncthreads();
  ushort_t* out = kT + (size_t)blk * 16384;
  for (int it = 0; it < 8; ++it) {
    const int e = it * 256 + tid;          // 2048 8B slots
    const int d = e >> 3, t8 = (e & 7) * 8;
    ushort4 lo, hi;
    lo.x = kl[d][t8 + 0]; lo.y = kl[d][t8 + 1]; lo.z = kl[d][t8 + 2]; lo.w = kl[d][t8 + 3];
    hi.x = kl[d][t8 + 4]; hi.y = kl[d][t8 + 5]; hi.z = kl[d][t8 + 6]; hi.w = kl[d][t8 + 7];
    *(ushort4*)(out + (size_t)d * 64 + t8)     = lo;
    *(ushort4*)(out + (size_t)d * 64 + t8 + 4) = hi;
  }
}

// ---------------------------------------------------------------------------
// vT[bh][e 512][n 2048] = v16[b, n, h*512+e]  — LDS transpose
// ---------------------------------------------------------------------------
__global__ __launch_bounds__(256) void pack_vT(const ushort_t* __restrict__ v16,
    ushort_t* __restrict__ vT) {
  const int blk = blockIdx.x;
  const int eh = blk & 1, c = (blk >> 1) & 31, bh = blk >> 6;
  const int b = bh >> 2, h = bh & 3;
  __shared__ ushort_t vl[256][68];
  const int tid = threadIdx.x;
  const ushort_t* vb = v16 + (size_t)(b * N_ + c * C_) * 2048 + h * 512 + eh * 256;
  for (int it = 0; it < 8; ++it) {
    const int e = it * 256 + tid;          // 2048 16B slots (64 s x 32 per row)
    const int s = e >> 5, c8 = (e & 31) * 8;
    bf16x8 val = *(const bf16x8*)(vb + (size_t)s * 2048 + c8);
#pragma unroll
    for (int j = 0; j < 8; ++j) vl[c8 + j][s] = (ushort_t)val[j];
  }
  __syncthreads();
  ushort_t* out = vT + (size_t)bh * 512 * 2048 + (size_t)(eh * 256) * 2048 + c * C_;
  for (int it = 0; it < 8; ++it) {
    const int e = it * 256 + tid;          // 2048 8B slots
    const int r = e >> 3, t8 = (e & 7) * 8;
    ushort4 lo, hi;
    lo.x = vl[r][t8 + 0]; lo.y = vl[r][t8 + 1]; lo.z = vl[r][t8 + 2]; lo.w = vl[r][t8 + 3];
    hi.x = vl[r][t8 + 4]; hi.y = vl[r][t8 + 5]; hi.z = vl[r][t8 + 6]; hi.w = vl[r][t8 + 7];
    *(ushort4*)(out + (size_t)r * 2048 + t8)     = lo;
    *(ushort4*)(out + (size_t)r * 2048 + t8 + 4) = hi;
  }
}

// ---------------------------------------------------------------------------
// Segmented MFMA chunk scan, EBLK=64.  grid = (16 bh, 8 vblk, 4 seg),
// wgid%8 = bh%8 (XCD affinity).  512 WGs = 2/CU.
// ---------------------------------------------------------------------------
__global__ __launch_bounds__(256) void scan_mfma(
    const ushort_t* __restrict__ q16,   // [8192][1024] pre-scaled bf16
    const ushort_t* __restrict__ kT,    // [bh][c][256][64] decayed bf16
    const ushort_t* __restrict__ vT,    // [bh][512][2048] bf16
    const ushort_t* __restrict__ ab,    // [bh*32+c][64][64] bf16
    const float*    __restrict__ gc,
    ushort_t* __restrict__ o,           // [8192][2048] bf16 (intra-segment part)
    float*    __restrict__ U) {         // [bh][seg 0..2][256][512] fp32
  const int bh = blockIdx.x, vblk = blockIdx.y, sg = blockIdx.z;
  const int b = bh >> 2, h = bh & 3;
  const int e0 = vblk * 64;
  const int c0 = sg * CSEG_;
  __shared__ ushort_t sbt[2][64][264];  // S^T bf16 double buffer (67.6 KB)
  __shared__ float egts[NC_];
  const int tid = threadIdx.x;
  const int w = tid >> 6, l = tid & 63;
  const int frow = l & 15, fgrp = l >> 4;

  for (int i = tid; i < 2 * 64 * 264 / 2; i += 256) ((unsigned*)&sbt[0][0][0])[i] = 0u;
  if (tid < NC_) egts[tid] = expf(gc[(size_t)bh * N_ + tid * C_ + 63]);
  f32x4 s_acc[4][4];
#pragma unroll
  for (int sm = 0; sm < 4; ++sm)
#pragma unroll
    for (int sn = 0; sn < 4; ++sn) s_acc[sm][sn] = f32x4{0.f, 0.f, 0.f, 0.f};
  __syncthreads();

  const ushort_t* qbase = q16 + (size_t)(b * N_) * 1024 + h * 256;
  const ushort_t* kbase = kT + (size_t)bh * NC_ * 16384;
  const ushort_t* vbase = vT + (size_t)bh * 512 * 2048 + (size_t)e0 * 2048;
  const ushort_t* abase = ab + (size_t)bh * NC_ * 4096;
  ushort_t*       obase = o + (size_t)(b * N_) * 2048 + h * 512 + e0;

  for (int c = c0; c < c0 + CSEG_; ++c) {
    const float egt = egts[c];
    const ushort_t (*srd)[264] = sbt[(c & 1) ^ 1];   // state after chunk c-1
    ushort_t (*swr)[264] = sbt[c & 1];               // state after chunk c

    // ---- shared operand loads for this chunk (amortized over 4 n-blocks)
    bf16x8 bv[2][4], aa[2], aq[8];
#pragma unroll
    for (int kt = 0; kt < 2; ++kt)
#pragma unroll
      for (int n = 0; n < 4; ++n)
        bv[kt][n] = *(const bf16x8*)(vbase + (size_t)(n * 16 + frow) * 2048 +
                                     c * C_ + kt * 32 + fgrp * 8);
#pragma unroll
    for (int kt = 0; kt < 2; ++kt)
      aa[kt] = *(const bf16x8*)(abase + (size_t)c * 4096 + (w * 16 + frow) * 64 + kt * 32 + fgrp * 8);
#pragma unroll
    for (int kk = 0; kk < 8; ++kk)
      aq[kk] = *(const bf16x8*)(qbase + (size_t)(c * C_ + w * 16 + frow) * 1024 + kk * 32 + fgrp * 8);

    // ---- o = A@v + q@Sb   (wave w: o rows w*16..+16, cols e0..e0+64)
#pragma unroll
    for (int n = 0; n < 4; ++n) {
      f32x4 oa = f32x4{0.f, 0.f, 0.f, 0.f};
#pragma unroll
      for (int kt = 0; kt < 2; ++kt) oa = mfma16(aa[kt], bv[kt][n], oa);
#pragma unroll
      for (int kk = 0; kk < 8; ++kk) {
        bf16x8 bs = *(const bf16x8*)(&srd[n * 16 + frow][kk * 32 + fgrp * 8]);
        oa = mfma16(aq[kk], bs, oa);
      }
#pragma unroll
      for (int j = 0; j < 4; ++j)
        obase[(size_t)(c * C_ + w * 16 + fgrp * 4 + j) * 2048 + n * 16 + frow] = f2bf(oa[j]);
    }

    // ---- S = e^gt * S + kT @ v   (wave w: d rows w*64..+64, all 64 e)
#pragma unroll
    for (int sm = 0; sm < 4; ++sm)
#pragma unroll
      for (int sn = 0; sn < 4; ++sn)
#pragma unroll
        for (int j = 0; j < 4; ++j) s_acc[sm][sn][j] *= egt;
#pragma unroll
    for (int kt = 0; kt < 2; ++kt)
#pragma unroll
      for (int sm = 0; sm < 4; ++sm) {
        bf16x8 ak = *(const bf16x8*)(kbase + (size_t)c * 16384 +
                                     (size_t)(w * 64 + sm * 16 + frow) * 64 + kt * 32 + fgrp * 8);
#pragma unroll
        for (int sn = 0; sn < 4; ++sn)
          s_acc[sm][sn] = mfma16(ak, bv[kt][sn], s_acc[sm][sn]);
      }

    // ---- publish S^T bf16 into the write buffer
#pragma unroll
    for (int sm = 0; sm < 4; ++sm)
#pragma unroll
      for (int sn = 0; sn < 4; ++sn) {
        ushort4 pk;
        pk.x = f2bf(s_acc[sm][sn][0]); pk.y = f2bf(s_acc[sm][sn][1]);
        pk.z = f2bf(s_acc[sm][sn][2]); pk.w = f2bf(s_acc[sm][sn][3]);
        *(ushort4*)&swr[sn * 16 + frow][w * 64 + sm * 16 + fgrp * 4] = pk;
      }
    __syncthreads();   // publishes visible; next chunk reads swr as srd
  }

  // ---- write segment-final state U (fp32) for segments 0..2
  if (sg < NSEG_ - 1) {
    float* ub = U + (size_t)(bh * (NSEG_ - 1) + sg) * 256 * 512;
#pragma unroll
    for (int sm = 0; sm < 4; ++sm)
#pragma unroll
      for (int sn = 0; sn < 4; ++sn)
#pragma unroll
        for (int j = 0; j < 4; ++j)
          ub[(size_t)(w * 64 + sm * 16 + fgrp * 4 + j) * 512 + e0 + sn * 16 + frow] =
              s_acc[sm][sn][j];
  }
}

// ---------------------------------------------------------------------------
// Combine boundary states: S_in(s+1) = E_s * S_in(s) + U_s, store S_in^T bf16
// in B-fragment layout [bh][s 0..2][vb of 16e][16 e][256 d].  grid (16, 32).
// ---------------------------------------------------------------------------
__global__ __launch_bounds__(256) void combine_kernel(const float* __restrict__ U,
    const float* __restrict__ gc, ushort_t* __restrict__ SinT) {
  const int bh = blockIdx.x, vb = blockIdx.y;
  const int d = threadIdx.x;            // 0..255
  float S[16];
#pragma unroll
  for (int e = 0; e < 16; ++e) S[e] = 0.f;
  for (int s = 0; s < NSEG_ - 1; ++s) {
    float gsum = 0.f;
    for (int c = s * CSEG_; c < (s + 1) * CSEG_; ++c)
      gsum += gc[(size_t)bh * N_ + c * C_ + 63];
    const float E = expf(gsum);
    const float* u = U + (size_t)(bh * (NSEG_ - 1) + s) * 256 * 512 + (size_t)d * 512 + vb * 16;
    ushort_t* out = SinT + (size_t)((bh * (NSEG_ - 1) + s) * 32 + vb) * 4096;
#pragma unroll
    for (int e = 0; e < 16; ++e) {
      S[e] = E * S[e] + u[e];
      out[e * 256 + d] = f2bf(S[e]);
    }
  }
}

// ---------------------------------------------------------------------------
// Cross-segment correction: o[t] += D_c * (q16[t] @ S_in(seg)).
// grid (16 bh, 32 vb, 3), seg = z+1.  256 thr = 4 waves.
// ---------------------------------------------------------------------------
__global__ __launch_bounds__(256) void correct_kernel(
    const ushort_t* __restrict__ q16, const ushort_t* __restrict__ SinT,
    const float* __restrict__ gc, ushort_t* __restrict__ o) {
  const int bh = blockIdx.x, vb = blockIdx.y, z = blockIdx.z;
  const int sg = z + 1, c0 = sg * CSEG_;
  const int b = bh >> 2, h = bh & 3;
  __shared__ ushort_t sT[16][264];
  __shared__ float dseg[CSEG_];
  const int tid = threadIdx.x;
  const int w = tid >> 6, l = tid & 63;
  const int frow = l & 15, fgrp = l >> 4;

  {  // stage S_in^T slice: thread t covers e = t>>4, d = (t&15)*16 .. +16
    const ushort_t* src = SinT + (size_t)((bh * (NSEG_ - 1) + z) * 32 + vb) * 4096;
    const int e = tid >> 4, dbase = (tid & 15) * 16;
    bf16x8 v0 = *(const bf16x8*)(src + e * 256 + dbase);
    bf16x8 v1 = *(const bf16x8*)(src + e * 256 + dbase + 8);
    *(bf16x8*)&sT[e][dbase]     = v0;
    *(bf16x8*)&sT[e][dbase + 8] = v1;
  }
  if (tid < CSEG_) {
    float s = 0.f;
    for (int i = 0; i < tid; ++i) s += gc[(size_t)bh * N_ + (c0 + i) * C_ + 63];
    dseg[tid] = expf(s);
  }
  __syncthreads();

  const ushort_t* qbase = q16 + (size_t)(b * N_) * 1024 + h * 256;
  ushort_t* obase = o + (size_t)(b * N_) * 2048 + h * 512 + vb * 16;

  for (int c = c0; c < c0 + CSEG_; ++c) {
    const float D = dseg[c - c0];
    f32x4 oa = f32x4{0.f, 0.f, 0.f, 0.f};
#pragma unroll
    for (int kk = 0; kk < 8; ++kk) {
      bf16x8 aq = *(const bf16x8*)(qbase + (size_t)(c * C_ + w * 16 + frow) * 1024 + kk * 32 + fgrp * 8);
      bf16x8 bs = *(const bf16x8*)(&sT[frow][kk * 32 + fgrp * 8]);
      oa = mfma16(aq, bs, oa);
    }
#pragma unroll
    for (int j = 0; j < 4; ++j) {
      const size_t idx = (size_t)(c * C_ + w * 16 + fgrp * 4 + j) * 2048 + frow;
      obase[idx] = f2bf(bf2f(obase[idx]) + D * oa[j]);
    }
  }
}

// ---------------------------------------------------------------------------
// ob(bf16) <- RMSNorm(o bf16)*gnorm_w * swish(g fp32)
// ---------------------------------------------------------------------------
__global__ __launch_bounds__(256) void normgate_kernel(const ushort_t* __restrict__ o,
    const float* __restrict__ g, const float* __restrict__ w,
    ushort_t* __restrict__ ob) {
  const int blk = blockIdx.x;
  const size_t base = (size_t)blk * DV_;
  const int tid = threadIdx.x;
  __shared__ float red2[256];
  const float v0 = bf2f(o[base + tid]), v1 = bf2f(o[base + tid + 256]);
  red2[tid] = v0 * v0 + v1 * v1;
  __syncthreads();
  for (int off = 128; off; off >>= 1) {
    if (tid < off) red2[tid] += red2[tid + off];
    __syncthreads();
  }
  const float rms = rsqrtf(red2[0] * (1.0f / 512.0f) + 1e-5f);
  const float g0 = g[base + tid], g1 = g[base + tid + 256];
  const float sw0 = g0 / (1.f + expf(-g0));
  const float sw1 = g1 / (1.f + expf(-g1));
  ob[base + tid]       = f2bf(v0 * rms * w[tid] * sw0);
  ob[base + tid + 256] = f2bf(v1 * rms * w[tid + 256] * sw1);
}

// ---------------------------------------------------------------------------
// Workspace (float units), total 51,445,760 fl = 196.25 MiB (R5-proven size):
//   gk 32K | gc 32K | qk16 8.39M | v16 8.39M | o 8.39M | ab16 1.05M |
//   q16 4.19M | kTp 4.19M | vTp 8.39M | xb 4.19M | W*T 4.19M
// Aliases (time-disjoint, verified against launch order):
//   U    (6.29M fp32) = qk16 region  [qk16 dead after a_mfma/pack_q16/pack_kT]
//   SinT (3.15M fl)   = v16 region   [v16 dead after pack_vT]
//   g    (16.78M fp32)= q16+kTp+vTp  [all dead after correct_kernel; exact fit]
//   ob   (bf16)       = qk16 region  [U dead after combine_kernel]
// ---------------------------------------------------------------------------
extern "C" void kernel_launch(void* const* d_in, const int* in_sizes, int n_in,
                              void* d_out, int out_size, void* d_ws, size_t ws_size,
                              hipStream_t stream) {
  (void)in_sizes; (void)n_in; (void)out_size; (void)ws_size;
  const float* x    = (const float*)d_in[0];
  const float* Wq   = (const float*)d_in[1];
  const float* Wk   = (const float*)d_in[2];
  const float* Wv   = (const float*)d_in[3];
  const float* Wg   = (const float*)d_in[4];
  const float* Wgk  = (const float*)d_in[5];
  const float* bgk  = (const float*)d_in[6];
  const float* Wo   = (const float*)d_in[7];
  const float* gw   = (const float*)d_in[8];

  float* ws = (float*)d_ws;
  size_t off = 0;
  float* gk = ws + off; off += (size_t)16 * N_;
  float* gc = ws + off; off += (size_t)16 * N_;
  ushort_t* qk16 = (ushort_t*)(ws + off); off += (size_t)M_ * 2048 / 2;
  ushort_t* v16  = (ushort_t*)(ws + off); off += (size_t)M_ * 2048 / 2;
  ushort_t* o    = (ushort_t*)(ws + off); off += (size_t)M_ * 2048 / 2;
  ushort_t* ab16 = (ushort_t*)(ws + off); off += (size_t)16 * NC_ * 4096 / 2;
  ushort_t* q16  = (ushort_t*)(ws + off); off += (size_t)M_ * 1024 / 2;
  ushort_t* kTp  = (ushort_t*)(ws + off); off += (size_t)16 * NC_ * 16384 / 2;
  ushort_t* vTp  = (ushort_t*)(ws + off); off += (size_t)16 * 512 * 2048 / 2;
  ushort_t* xb   = (ushort_t*)(ws + off); off += (size_t)M_ * HID_ / 2;
  ushort_t* WqT  = (ushort_t*)(ws + off); off += (size_t)1024 * 1024 / 2;
  ushort_t* WkT  = (ushort_t*)(ws + off); off += (size_t)1024 * 1024 / 2;
  ushort_t* WvT  = (ushort_t*)(ws + off); off += (size_t)2048 * 1024 / 2;
  ushort_t* WgT  = (ushort_t*)(ws + off); off += (size_t)2048 * 1024 / 2;
  ushort_t* WoT  = (ushort_t*)(ws + off); off += (size_t)1024 * 2048 / 2;
  // time-disjoint aliases (see table above)
  float*    U    = (float*)qk16;          // 6.29M fl, fits qk16 (8.39M)
  ushort_t* SinT = v16;                   // 3.15M fl, fits v16 (8.39M)
  float*    g    = (float*)q16;           // 16.78M fl over q16+kTp+vTp (exact)
  ushort_t* ob   = qk16;                  // over qk16 (after combine)

  dim3 thr(256);
  conv_to_bf16<<<M_ * HID_ / 1024, thr, 0, stream>>>(x, xb);
  transp_bf16<<<dim3(32, 32), thr, 0, stream>>>(Wq, WqT, 1024, 1024);
  transp_bf16<<<dim3(32, 32), thr, 0, stream>>>(Wk, WkT, 1024, 1024);
  transp_bf16<<<dim3(64, 32), thr, 0, stream>>>(Wv, WvT, 1024, 2048);
  transp_bf16<<<dim3(64, 32), thr, 0, stream>>>(Wg, WgT, 1024, 2048);
  transp_bf16<<<dim3(32, 64), thr, 0, stream>>>(Wo, WoT, 2048, 1024);

  // fused q|k projection: BT = [WqT ; WkT] (adjacent), bf16 out
  gemm_mfma<true><<<dim3(16, 64), thr, 0, stream>>>(xb, WqT, qk16, 2048, 1024);
  gk_kernel<<<M_, thr, 0, stream>>>(x, Wgk, bgk, gk);
  cumsum_kernel<<<16, 64, 0, stream>>>(gk, gc);
  a_mfma<<<16 * NC_, thr, 0, stream>>>(qk16, gc, ab16);
  pack_q16<<<M_ * 1024 / 2048, thr, 0, stream>>>(qk16, gc, q16);
  pack_kT<<<16 * NC_, thr, 0, stream>>>(qk16, gc, kTp);
  gemm_mfma<true><<<dim3(16, 64), thr, 0, stream>>>(xb, WvT, v16, 2048, 1024);
  pack_vT<<<16 * NC_ * 2, thr, 0, stream>>>(v16, vTp);
  scan_mfma<<<dim3(16, 8, NSEG_), thr, 0, stream>>>(q16, kTp, vTp, ab16, gc, o, U);
  combine_kernel<<<dim3(16, 32), thr, 0, stream>>>(U, gc, SinT);
  correct_kernel<<<dim3(16, 32, NSEG_ - 1), thr, 0, stream>>>(q16, SinT, gc, o);
  gemm_mfma<false><<<dim3(16, 64), thr, 0, stream>>>(xb, WgT, g, 2048, 1024);
  normgate_kernel<<<M_ * NH_, thr, 0, stream>>>(o, g, gw, ob);
  gemm_mfma<false><<<dim3(8, 64), thr, 0, stream>>>(ob, WoT, (float*)d_out, 1024, 2048);
}

// Round 12
// 476.213 us; speedup vs baseline: 1.3917x; 1.0963x over previous
//
#include <hip/hip_runtime.h>

// Problem constants (fixed by the reference)
constexpr int B_  = 4;
constexpr int N_  = 2048;
constexpr int HID_ = 1024;
constexpr int NH_ = 4;
constexpr int DK_ = 256;
constexpr int DV_ = 512;
constexpr int C_  = 64;     // chunk size
constexpr int NC_ = 32;     // chunks per sequence
constexpr int M_  = B_ * N_;  // 8192 rows
constexpr int NSEG_ = 4;    // scan segments
constexpr int CSEG_ = NC_ / NSEG_;  // 8 chunks per segment

using ushort_t = unsigned short;
typedef __attribute__((ext_vector_type(8))) short bf16x8;
typedef __attribute__((ext_vector_type(4))) float f32x4;

__device__ __forceinline__ ushort_t f2bf(float f) {
  union { float fv; unsigned u; } v; v.fv = f;
  unsigned r = v.u + 0x7FFFu + ((v.u >> 16) & 1u);   // round-to-nearest-even
  return (ushort_t)(r >> 16);
}
__device__ __forceinline__ float bf2f(ushort_t u) {
  union { unsigned u; float f; } v; v.u = ((unsigned)u) << 16; return v.f;
}

__device__ __forceinline__ void gload_lds16(const void* g, void* l) {
  __builtin_amdgcn_global_load_lds(
      (const __attribute__((address_space(1))) unsigned int*)g,
      (__attribute__((address_space(3))) unsigned int*)l, 16, 0, 0);
}

__device__ __forceinline__ f32x4 mfma16(bf16x8 a, bf16x8 b, f32x4 c) {
  return __builtin_amdgcn_mfma_f32_16x16x32_bf16(a, b, c, 0, 0, 0);
}

// ---------------------------------------------------------------------------
// bf16 MFMA GEMM: C[M,N] = A[M,K] bf16 @ BT[N,K] bf16.  Out fp32 or bf16.
// 128x128 tile, BK=32, 256 thr = 4 waves, m97 2-barrier loop.
// ---------------------------------------------------------------------------
template<bool BF16OUT>
__global__ __launch_bounds__(256) void gemm_mfma(
    const ushort_t* __restrict__ A, const ushort_t* __restrict__ BT,
    void* __restrict__ CV, int N, int K) {
  __shared__ ushort_t Asl[128 * 32];
  __shared__ ushort_t Bsl[128 * 32];
  const int tid = threadIdx.x;
  const int wave = tid >> 6, lane = tid & 63;
  const size_t brow = (size_t)blockIdx.y * 128;
  const size_t bcol = (size_t)blockIdx.x * 128;
  const int wr = (wave >> 1) * 64, wc = (wave & 1) * 64;

  f32x4 acc[4][4];
#pragma unroll
  for (int m = 0; m < 4; ++m)
#pragma unroll
    for (int n = 0; n < 4; ++n) acc[m][n] = f32x4{0.f, 0.f, 0.f, 0.f};

  const int kk   = (lane & 3) * 8;     // staging k within tile
  const int frow = lane & 15;          // fragment row/col
  const int fk   = (lane >> 4) * 8;    // fragment k-slice

  for (int k0 = 0; k0 < K; k0 += 32) {
#pragma unroll
    for (int j = 0; j < 2; ++j) {
      const int cbase = j * 4 + wave;                 // 0..7 (wave-uniform)
      const int row   = (cbase * 64 + lane) >> 2;     // 0..127
      gload_lds16(A  + (brow + row) * K + k0 + kk, Asl + cbase * 512);
      gload_lds16(BT + (bcol + row) * K + k0 + kk, Bsl + cbase * 512);
    }
    __syncthreads();

    bf16x8 af[4], bfr[4];
#pragma unroll
    for (int m = 0; m < 4; ++m)
      af[m] = *(const bf16x8*)(Asl + (wr + m * 16 + frow) * 32 + fk);
#pragma unroll
    for (int n = 0; n < 4; ++n)
      bfr[n] = *(const bf16x8*)(Bsl + (wc + n * 16 + frow) * 32 + fk);
#pragma unroll
    for (int m = 0; m < 4; ++m)
#pragma unroll
      for (int n = 0; n < 4; ++n)
        acc[m][n] = mfma16(af[m], bfr[n], acc[m][n]);
    __syncthreads();
  }

  const int crow = (lane >> 4) * 4;
  const int ccol = lane & 15;
#pragma unroll
  for (int m = 0; m < 4; ++m)
#pragma unroll
    for (int n = 0; n < 4; ++n) {
      const size_t base = (brow + wr + m * 16 + crow) * (size_t)N + (bcol + wc + n * 16 + ccol);
      if constexpr (BF16OUT) {
        ushort_t* Out = (ushort_t*)CV;
#pragma unroll
        for (int j = 0; j < 4; ++j) Out[base + (size_t)j * N] = f2bf(acc[m][n][j]);
      } else {
        float* Out = (float*)CV;
#pragma unroll
        for (int j = 0; j < 4; ++j) Out[base + (size_t)j * N] = acc[m][n][j];
      }
    }
}

// ---------------------------------------------------------------------------
// fp32 -> bf16 elementwise (4 elems/thread)
// ---------------------------------------------------------------------------
__global__ __launch_bounds__(256) void conv_to_bf16(const float* __restrict__ in,
    ushort_t* __restrict__ out) {
  const size_t i = ((size_t)blockIdx.x * 256 + threadIdx.x) * 4;
  float4 v = *(const float4*)(in + i);
  ushort4 r;
  r.x = f2bf(v.x); r.y = f2bf(v.y); r.z = f2bf(v.z); r.w = f2bf(v.w);
  *(ushort4*)(out + i) = r;
}

// ---------------------------------------------------------------------------
// W[K,N] fp32 -> WT[N,K] bf16 (tiled transpose)
// ---------------------------------------------------------------------------
__global__ __launch_bounds__(256) void transp_bf16(const float* __restrict__ W,
    ushort_t* __restrict__ WT, int K, int N) {
  __shared__ float tile[32][33];
  const int n0 = blockIdx.x * 32, k0 = blockIdx.y * 32;
  const int tx = threadIdx.x & 31, ty = threadIdx.x >> 5;
#pragma unroll
  for (int i = 0; i < 32; i += 8)
    tile[ty + i][tx] = W[(size_t)(k0 + ty + i) * N + n0 + tx];
  __syncthreads();
#pragma unroll
  for (int i = 0; i < 32; i += 8)
    WT[(size_t)(n0 + ty + i) * K + k0 + tx] = f2bf(tile[tx][ty + i]);
}

// ---------------------------------------------------------------------------
// gk[b,h,n] = logsigmoid(x[b,n,:]·Wgk[:,h] + bgk[h]) / 16
// ---------------------------------------------------------------------------
__global__ __launch_bounds__(256) void gk_kernel(const float* __restrict__ x,
    const float* __restrict__ Wgk, const float* __restrict__ bgk,
    float* __restrict__ gkbuf) {
  const int row  = blockIdx.x;
  const int b    = row / N_;
  const int n    = row - b * N_;
  const int tid  = threadIdx.x;
  const int wv   = tid >> 6;
  const int ln   = tid & 63;
  __shared__ float red2[256];
  const float* xr = x + (size_t)row * HID_;
  float s = 0.f;
  for (int i = ln; i < HID_; i += 64) s += xr[i] * Wgk[i * NH_ + wv];
  red2[tid] = s;
  __syncthreads();
  for (int off = 32; off; off >>= 1) {
    if (ln < off) red2[tid] += red2[tid + off];
    __syncthreads();
  }
  if (ln == 0) {
    float z  = red2[wv * 64] + bgk[wv];
    float ls = fminf(z, 0.f) - log1pf(expf(-fabsf(z)));
    gkbuf[((size_t)(b * NH_ + wv)) * N_ + n] = ls * (1.0f / 16.0f);
  }
}

// ---------------------------------------------------------------------------
// per-(bh,chunk) inclusive cumsum of gk
// ---------------------------------------------------------------------------
__global__ __launch_bounds__(64) void cumsum_kernel(const float* __restrict__ gkbuf,
                                                    float* __restrict__ gcbuf) {
  const int bh = blockIdx.x;
  const int c  = threadIdx.x;
  if (c < NC_) {
    const size_t base = (size_t)bh * N_ + c * C_;
    float acc = 0.f;
    for (int t = 0; t < C_; ++t) { acc += gkbuf[base + t]; gcbuf[base + t] = acc; }
  }
}

// ---------------------------------------------------------------------------
// MFMA A-matrix: A[bh,c,t,s] = (s<=t) ? (q_t·k_s)*(1/16)*exp(gc_t-gc_s) : 0
// q,k read as bf16 fragments from fused qkv16 [8192][4096]
// (q cols 0..1023, k cols 1024..2047, v cols 2048..4095).
// ---------------------------------------------------------------------------
__global__ __launch_bounds__(256) void a_mfma(const ushort_t* __restrict__ qkv16,
    const float* __restrict__ gc, ushort_t* __restrict__ Abuf) {
  const int blk = blockIdx.x;
  const int bh  = blk >> 5, c = blk & 31;
  const int b   = bh >> 2, h = bh & 3;
  __shared__ float gcs[64];
  const int tid = threadIdx.x;
  const int w = tid >> 6, l = tid & 63;
  const int frow = l & 15, fgrp = l >> 4;
  if (tid < 64) gcs[tid] = gc[(size_t)bh * N_ + c * C_ + tid];
  __syncthreads();

  const size_t rbase = (size_t)(b * N_ + c * C_);
  bf16x8 aqr[8];
#pragma unroll
  for (int kk = 0; kk < 8; ++kk)
    aqr[kk] = *(const bf16x8*)(qkv16 + (rbase + w * 16 + frow) * 4096 +
                               h * 256 + kk * 32 + fgrp * 8);

  ushort_t* ab = Abuf + (size_t)blk * 4096;
  const float scl = 0.0625f;
#pragma unroll
  for (int n = 0; n < 4; ++n) {
    f32x4 acc = f32x4{0.f, 0.f, 0.f, 0.f};
#pragma unroll
    for (int kk = 0; kk < 8; ++kk) {
      bf16x8 bk = *(const bf16x8*)(qkv16 + (rbase + n * 16 + frow) * 4096 +
                                   1024 + h * 256 + kk * 32 + fgrp * 8);
      acc = mfma16(aqr[kk], bk, acc);
    }
    const int s = n * 16 + frow;
    const float gcss = gcs[s];
#pragma unroll
    for (int j = 0; j < 4; ++j) {
      const int t = w * 16 + fgrp * 4 + j;
      const float val = (s <= t) ? acc[j] * scl * expf(gcs[t] - gcss) : 0.f;
      ab[(size_t)t * 64 + s] = f2bf(val);
    }
  }
}

// ---------------------------------------------------------------------------
// q16[row][col] = bf16( q_raw(bf16) * (1/16) * e^gc ), q_raw = qkv16 cols 0..1023
// ---------------------------------------------------------------------------
__global__ __launch_bounds__(256) void pack_q16(const ushort_t* __restrict__ qkv16,
    const float* __restrict__ gc, ushort_t* __restrict__ q16) {
  const size_t i8 = ((size_t)blockIdx.x * 256 + threadIdx.x) * 8;   // < M*1024
  const int row = (int)(i8 >> 10);
  const int col = (int)(i8 & 1023);
  const int b = row >> 11, n = row & 2047;
  const int h = col >> 8;
  const float f = 0.0625f * expf(gc[(size_t)(b * NH_ + h) * N_ + n]);
  bf16x8 v = *(const bf16x8*)(qkv16 + (size_t)row * 4096 + col);
  ushort_t r[8];
#pragma unroll
  for (int j = 0; j < 8; ++j) r[j] = f2bf(bf2f((ushort_t)v[j]) * f);
  *(bf16x8*)(q16 + i8) = *(bf16x8*)r;
}

// ---------------------------------------------------------------------------
// kT[bh][c][d 256][t 64] = bf16( k_raw(bf16) * e^(gt - gc_t) ) — LDS transpose
// k_raw = qkv16 cols 1024..2047.
// ---------------------------------------------------------------------------
__global__ __launch_bounds__(256) void pack_kT(const ushort_t* __restrict__ qkv16,
    const float* __restrict__ gc, ushort_t* __restrict__ kT) {
  const int blk = blockIdx.x;
  const int bh = blk >> 5, c = blk & 31;
  const int b = bh >> 2, h = bh & 3;
  __shared__ ushort_t kl[256][68];
  __shared__ float fk[64];
  const int tid = threadIdx.x;
  if (tid < 64) {
    const float gct = gc[(size_t)bh * N_ + c * C_ + tid];
    const float gt  = gc[(size_t)bh * N_ + c * C_ + 63];
    fk[tid] = expf(gt - gct);
  }
  __syncthreads();
  const ushort_t* kb = qkv16 + (size_t)(b * N_ + c * C_) * 4096 + 1024 + h * 256;
  for (int it = 0; it < 8; ++it) {
    const int e = it * 256 + tid;          // 2048 8-elem slots
    const int t = e >> 5, d8 = (e & 31) * 8;
    bf16x8 kv = *(const bf16x8*)(kb + (size_t)t * 4096 + d8);
    const float f = fk[t];
#pragma unroll
    for (int j = 0; j < 8; ++j) kl[d8 + j][t] = f2bf(bf2f((ushort_t)kv[j]) * f);
  }
  __syncthreads();
  ushort_t* out = kT + (size_t)blk * 16384;
  for (int it = 0; it < 8; ++it) {
    const int e = it * 256 + tid;          // 2048 8B slots
    const int d = e >> 3, t8 = (e & 7) * 8;
    ushort4 lo, hi;
    lo.x = kl[d][t8 + 0]; lo.y = kl[d][t8 + 1]; lo.z = kl[d][t8 + 2]; lo.w = kl[d][t8 + 3];
    hi.x = kl[d][t8 + 4]; hi.y = kl[d][t8 + 5]; hi.z = kl[d][t8 + 6]; hi.w = kl[d][t8 + 7];
    *(ushort4*)(out + (size_t)d * 64 + t8)     = lo;
    *(ushort4*)(out + (size_t)d * 64 + t8 + 4) = hi;
  }
}

// ---------------------------------------------------------------------------
// vT[bh][e 512][n 2048] = v_raw[b, n, h*512+e], v_raw = qkv16 cols 2048..4095
// ---------------------------------------------------------------------------
__global__ __launch_bounds__(256) void pack_vT(const ushort_t* __restrict__ qkv16,
    ushort_t* __restrict__ vT) {
  const int blk = blockIdx.x;
  const int eh = blk & 1, c = (blk >> 1) & 31, bh = blk >> 6;
  const int b = bh >> 2, h = bh & 3;
  __shared__ ushort_t vl[256][68];
  const int tid = threadIdx.x;
  const ushort_t* vb = qkv16 + (size_t)(b * N_ + c * C_) * 4096 + 2048 + h * 512 + eh * 256;
  for (int it = 0; it < 8; ++it) {
    const int e = it * 256 + tid;          // 2048 16B slots (64 s x 32 per row)
    const int s = e >> 5, c8 = (e & 31) * 8;
    bf16x8 val = *(const bf16x8*)(vb + (size_t)s * 4096 + c8);
#pragma unroll
    for (int j = 0; j < 8; ++j) vl[c8 + j][s] = (ushort_t)val[j];
  }
  __syncthreads();
  ushort_t* out = vT + (size_t)bh * 512 * 2048 + (size_t)(eh * 256) * 2048 + c * C_;
  for (int it = 0; it < 8; ++it) {
    const int e = it * 256 + tid;          // 2048 8B slots
    const int r = e >> 3, t8 = (e & 7) * 8;
    ushort4 lo, hi;
    lo.x = vl[r][t8 + 0]; lo.y = vl[r][t8 + 1]; lo.z = vl[r][t8 + 2]; lo.w = vl[r][t8 + 3];
    hi.x = vl[r][t8 + 4]; hi.y = vl[r][t8 + 5]; hi.z = vl[r][t8 + 6]; hi.w = vl[r][t8 + 7];
    *(ushort4*)(out + (size_t)r * 2048 + t8)     = lo;
    *(ushort4*)(out + (size_t)r * 2048 + t8 + 4) = hi;
  }
}

// ---------------------------------------------------------------------------
// Segmented MFMA chunk scan, EBLK=64, with next-chunk aq prefetch.
// grid = (16 bh, 8 vblk, 4 seg), wgid%8 = bh%8 (XCD affinity).  512 WGs = 2/CU.
// ---------------------------------------------------------------------------
#define LOAD_AQ(cc, dst)                                                       \
  do {                                                                         \
    _Pragma("unroll")                                                          \
    for (int kk = 0; kk < 8; ++kk)                                             \
      dst[kk] = *(const bf16x8*)(qbase + (size_t)((cc) * C_ + w * 16 + frow) * 1024 + \
                                 kk * 32 + fgrp * 8);                          \
  } while (0)

__global__ __launch_bounds__(256) void scan_mfma(
    const ushort_t* __restrict__ q16,   // [8192][1024] pre-scaled bf16
    const ushort_t* __restrict__ kT,    // [bh][c][256][64] decayed bf16
    const ushort_t* __restrict__ vT,    // [bh][512][2048] bf16
    const ushort_t* __restrict__ ab,    // [bh*32+c][64][64] bf16
    const float*    __restrict__ gc,
    ushort_t* __restrict__ o,           // [8192][2048] bf16 (intra-segment part)
    float*    __restrict__ U) {         // [bh][seg 0..2][256][512] fp32
  const int bh = blockIdx.x, vblk = blockIdx.y, sg = blockIdx.z;
  const int b = bh >> 2, h = bh & 3;
  const int e0 = vblk * 64;
  const int c0 = sg * CSEG_;
  __shared__ ushort_t sbt[2][64][264];  // S^T bf16 double buffer (67.6 KB)
  __shared__ float egts[NC_];
  const int tid = threadIdx.x;
  const int w = tid >> 6, l = tid & 63;
  const int frow = l & 15, fgrp = l >> 4;

  for (int i = tid; i < 2 * 64 * 264 / 2; i += 256) ((unsigned*)&sbt[0][0][0])[i] = 0u;
  if (tid < NC_) egts[tid] = expf(gc[(size_t)bh * N_ + tid * C_ + 63]);
  f32x4 s_acc[4][4];
#pragma unroll
  for (int sm = 0; sm < 4; ++sm)
#pragma unroll
    for (int sn = 0; sn < 4; ++sn) s_acc[sm][sn] = f32x4{0.f, 0.f, 0.f, 0.f};
  __syncthreads();

  const ushort_t* qbase = q16 + (size_t)(b * N_) * 1024 + h * 256;
  const ushort_t* kbase = kT + (size_t)bh * NC_ * 16384;
  const ushort_t* vbase = vT + (size_t)bh * 512 * 2048 + (size_t)e0 * 2048;
  const ushort_t* abase = ab + (size_t)bh * NC_ * 4096;
  ushort_t*       obase = o + (size_t)(b * N_) * 2048 + h * 512 + e0;

  bf16x8 aqP[8];
  LOAD_AQ(c0, aqP);

  for (int c = c0; c < c0 + CSEG_; ++c) {
    const float egt = egts[c];
    const ushort_t (*srd)[264] = sbt[(c & 1) ^ 1];   // state after chunk c-1
    ushort_t (*swr)[264] = sbt[c & 1];               // state after chunk c

    // consume prefetched aq (SSA copy, no actual moves after regalloc)
    bf16x8 aq[8];
#pragma unroll
    for (int kk = 0; kk < 8; ++kk) aq[kk] = aqP[kk];

    // ---- remaining operand loads for this chunk
    bf16x8 bv[2][4], aa[2];
#pragma unroll
    for (int kt = 0; kt < 2; ++kt)
#pragma unroll
      for (int n = 0; n < 4; ++n)
        bv[kt][n] = *(const bf16x8*)(vbase + (size_t)(n * 16 + frow) * 2048 +
                                     c * C_ + kt * 32 + fgrp * 8);
#pragma unroll
    for (int kt = 0; kt < 2; ++kt)
      aa[kt] = *(const bf16x8*)(abase + (size_t)c * 4096 + (w * 16 + frow) * 64 + kt * 32 + fgrp * 8);

    // ---- o = A@v + q@Sb   (wave w: o rows w*16..+16, cols e0..e0+64)
#pragma unroll
    for (int n = 0; n < 4; ++n) {
      f32x4 oa = f32x4{0.f, 0.f, 0.f, 0.f};
#pragma unroll
      for (int kt = 0; kt < 2; ++kt) oa = mfma16(aa[kt], bv[kt][n], oa);
#pragma unroll
      for (int kk = 0; kk < 8; ++kk) {
        bf16x8 bs = *(const bf16x8*)(&srd[n * 16 + frow][kk * 32 + fgrp * 8]);
        oa = mfma16(aq[kk], bs, oa);
      }
#pragma unroll
      for (int j = 0; j < 4; ++j)
        obase[(size_t)(c * C_ + w * 16 + fgrp * 4 + j) * 2048 + n * 16 + frow] = f2bf(oa[j]);
    }

    // ---- S = e^gt * S + kT @ v   (wave w: d rows w*64..+64, all 64 e)
#pragma unroll
    for (int sm = 0; sm < 4; ++sm)
#pragma unroll
      for (int sn = 0; sn < 4; ++sn)
#pragma unroll
        for (int j = 0; j < 4; ++j) s_acc[sm][sn][j] *= egt;
#pragma unroll
    for (int kt = 0; kt < 2; ++kt)
#pragma unroll
      for (int sm = 0; sm < 4; ++sm) {
        bf16x8 ak = *(const bf16x8*)(kbase + (size_t)c * 16384 +
                                     (size_t)(w * 64 + sm * 16 + frow) * 64 + kt * 32 + fgrp * 8);
#pragma unroll
        for (int sn = 0; sn < 4; ++sn)
          s_acc[sm][sn] = mfma16(ak, bv[kt][sn], s_acc[sm][sn]);
      }

    // ---- prefetch next chunk's aq (issued before the barrier; consumed after)
    if (c + 1 < c0 + CSEG_) LOAD_AQ(c + 1, aqP);

    // ---- publish S^T bf16 into the write buffer
#pragma unroll
    for (int sm = 0; sm < 4; ++sm)
#pragma unroll
      for (int sn = 0; sn < 4; ++sn) {
        ushort4 pk;
        pk.x = f2bf(s_acc[sm][sn][0]); pk.y = f2bf(s_acc[sm][sn][1]);
        pk.z = f2bf(s_acc[sm][sn][2]); pk.w = f2bf(s_acc[sm][sn][3]);
        *(ushort4*)&swr[sn * 16 + frow][w * 64 + sm * 16 + fgrp * 4] = pk;
      }
    __syncthreads();   // publishes visible; next chunk reads swr as srd
  }

  // ---- write segment-final state U (fp32) for segments 0..2
  if (sg < NSEG_ - 1) {
    float* ub = U + (size_t)(bh * (NSEG_ - 1) + sg) * 256 * 512;
#pragma unroll
    for (int sm = 0; sm < 4; ++sm)
#pragma unroll
      for (int sn = 0; sn < 4; ++sn)
#pragma unroll
        for (int j = 0; j < 4; ++j)
          ub[(size_t)(w * 64 + sm * 16 + fgrp * 4 + j) * 512 + e0 + sn * 16 + frow] =
              s_acc[sm][sn][j];
  }
}

// ---------------------------------------------------------------------------
// Combine boundary states: S_in(s+1) = E_s * S_in(s) + U_s, store S_in^T bf16
// in B-fragment layout [bh][s 0..2][vb of 16e][16 e][256 d].  grid (16, 32).
// ---------------------------------------------------------------------------
__global__ __launch_bounds__(256) void combine_kernel(const float* __restrict__ U,
    const float* __restrict__ gc, ushort_t* __restrict__ SinT) {
  const int bh = blockIdx.x, vb = blockIdx.y;
  const int d = threadIdx.x;            // 0..255
  float S[16];
#pragma unroll
  for (int e = 0; e < 16; ++e) S[e] = 0.f;
  for (int s = 0; s < NSEG_ - 1; ++s) {
    float gsum = 0.f;
    for (int c = s * CSEG_; c < (s + 1) * CSEG_; ++c)
      gsum += gc[(size_t)bh * N_ + c * C_ + 63];
    const float E = expf(gsum);
    const float* u = U + (size_t)(bh * (NSEG_ - 1) + s) * 256 * 512 + (size_t)d * 512 + vb * 16;
    ushort_t* out = SinT + (size_t)((bh * (NSEG_ - 1) + s) * 32 + vb) * 4096;
#pragma unroll
    for (int e = 0; e < 16; ++e) {
      S[e] = E * S[e] + u[e];
      out[e * 256 + d] = f2bf(S[e]);
    }
  }
}

// ---------------------------------------------------------------------------
// Cross-segment correction: o[t] += D_c * (q16[t] @ S_in(seg)).
// grid (16 bh, 32 vb, 3), seg = z+1.  256 thr = 4 waves.
// ---------------------------------------------------------------------------
__global__ __launch_bounds__(256) void correct_kernel(
    const ushort_t* __restrict__ q16, const ushort_t* __restrict__ SinT,
    const float* __restrict__ gc, ushort_t* __restrict__ o) {
  const int bh = blockIdx.x, vb = blockIdx.y, z = blockIdx.z;
  const int sg = z + 1, c0 = sg * CSEG_;
  const int b = bh >> 2, h = bh & 3;
  __shared__ ushort_t sT[16][264];
  __shared__ float dseg[CSEG_];
  const int tid = threadIdx.x;
  const int w = tid >> 6, l = tid & 63;
  const int frow = l & 15, fgrp = l >> 4;

  {  // stage S_in^T slice
    const ushort_t* src = SinT + (size_t)((bh * (NSEG_ - 1) + z) * 32 + vb) * 4096;
    const int e = tid >> 4, dbase = (tid & 15) * 16;
    bf16x8 v0 = *(const bf16x8*)(src + e * 256 + dbase);
    bf16x8 v1 = *(const bf16x8*)(src + e * 256 + dbase + 8);
    *(bf16x8*)&sT[e][dbase]     = v0;
    *(bf16x8*)&sT[e][dbase + 8] = v1;
  }
  if (tid < CSEG_) {
    float s = 0.f;
    for (int i = 0; i < tid; ++i) s += gc[(size_t)bh * N_ + (c0 + i) * C_ + 63];
    dseg[tid] = expf(s);
  }
  __syncthreads();

  const ushort_t* qbase = q16 + (size_t)(b * N_) * 1024 + h * 256;
  ushort_t* obase = o + (size_t)(b * N_) * 2048 + h * 512 + vb * 16;

  for (int c = c0; c < c0 + CSEG_; ++c) {
    const float D = dseg[c - c0];
    f32x4 oa = f32x4{0.f, 0.f, 0.f, 0.f};
#pragma unroll
    for (int kk = 0; kk < 8; ++kk) {
      bf16x8 aq = *(const bf16x8*)(qbase + (size_t)(c * C_ + w * 16 + frow) * 1024 + kk * 32 + fgrp * 8);
      bf16x8 bs = *(const bf16x8*)(&sT[frow][kk * 32 + fgrp * 8]);
      oa = mfma16(aq, bs, oa);
    }
#pragma unroll
    for (int j = 0; j < 4; ++j) {
      const size_t idx = (size_t)(c * C_ + w * 16 + fgrp * 4 + j) * 2048 + frow;
      obase[idx] = f2bf(bf2f(obase[idx]) + D * oa[j]);
    }
  }
}

// ---------------------------------------------------------------------------
// ob(bf16) <- RMSNorm(o bf16)*gnorm_w * swish(g bf16)
// ---------------------------------------------------------------------------
__global__ __launch_bounds__(256) void normgate_kernel(const ushort_t* __restrict__ o,
    const ushort_t* __restrict__ g, const float* __restrict__ w,
    ushort_t* __restrict__ ob) {
  const int blk = blockIdx.x;
  const size_t base = (size_t)blk * DV_;
  const int tid = threadIdx.x;
  __shared__ float red2[256];
  const float v0 = bf2f(o[base + tid]), v1 = bf2f(o[base + tid + 256]);
  red2[tid] = v0 * v0 + v1 * v1;
  __syncthreads();
  for (int off = 128; off; off >>= 1) {
    if (tid < off) red2[tid] += red2[tid + off];
    __syncthreads();
  }
  const float rms = rsqrtf(red2[0] * (1.0f / 512.0f) + 1e-5f);
  const float g0 = bf2f(g[base + tid]), g1 = bf2f(g[base + tid + 256]);
  const float sw0 = g0 / (1.f + expf(-g0));
  const float sw1 = g1 / (1.f + expf(-g1));
  ob[base + tid]       = f2bf(v0 * rms * w[tid] * sw0);
  ob[base + tid + 256] = f2bf(v1 * rms * w[tid + 256] * sw1);
}

// ---------------------------------------------------------------------------
// Workspace (float units), total 51,445,760 fl = 196.25 MiB (R5-proven size):
//   gk 32K | gc 32K | qkv16 16.78M | o 8.39M | ab16 1.05M |
//   q16 4.19M | kTp 4.19M | vTp 8.39M | xb 4.19M | W*T 4.19M
// Aliases (time-disjoint, verified against launch order):
//   U    (6.29M fp32) = qkv16[0..]      [qkv16 dead after pack_vT]
//   SinT (3.15M fl)   = qkv16[+6.29M]   [disjoint from U]
//   g16  (8.39M fl)   = q16+kTp         [both dead after correct; exact fit]
//   ob   (8.39M fl)   = vTp             [dead after scan; exact fit]
// ---------------------------------------------------------------------------
extern "C" void kernel_launch(void* const* d_in, const int* in_sizes, int n_in,
                              void* d_out, int out_size, void* d_ws, size_t ws_size,
                              hipStream_t stream) {
  (void)in_sizes; (void)n_in; (void)out_size; (void)ws_size;
  const float* x    = (const float*)d_in[0];
  const float* Wq   = (const float*)d_in[1];
  const float* Wk   = (const float*)d_in[2];
  const float* Wv   = (const float*)d_in[3];
  const float* Wg   = (const float*)d_in[4];
  const float* Wgk  = (const float*)d_in[5];
  const float* bgk  = (const float*)d_in[6];
  const float* Wo   = (const float*)d_in[7];
  const float* gw   = (const float*)d_in[8];

  float* ws = (float*)d_ws;
  size_t off = 0;
  float* gk = ws + off; off += (size_t)16 * N_;
  float* gc = ws + off; off += (size_t)16 * N_;
  ushort_t* qkv16 = (ushort_t*)(ws + off); size_t qkv_off = off; off += (size_t)M_ * 4096 / 2;
  ushort_t* o    = (ushort_t*)(ws + off); off += (size_t)M_ * 2048 / 2;
  ushort_t* ab16 = (ushort_t*)(ws + off); off += (size_t)16 * NC_ * 4096 / 2;
  ushort_t* q16  = (ushort_t*)(ws + off); size_t q16_off = off; off += (size_t)M_ * 1024 / 2;
  ushort_t* kTp  = (ushort_t*)(ws + off); off += (size_t)16 * NC_ * 16384 / 2;
  ushort_t* vTp  = (ushort_t*)(ws + off); size_t vTp_off = off; off += (size_t)16 * 512 * 2048 / 2;
  ushort_t* xb   = (ushort_t*)(ws + off); off += (size_t)M_ * HID_ / 2;
  ushort_t* WqT  = (ushort_t*)(ws + off); off += (size_t)1024 * 1024 / 2;
  ushort_t* WkT  = (ushort_t*)(ws + off); off += (size_t)1024 * 1024 / 2;
  ushort_t* WvT  = (ushort_t*)(ws + off); off += (size_t)2048 * 1024 / 2;
  ushort_t* WgT  = (ushort_t*)(ws + off); off += (size_t)2048 * 1024 / 2;
  ushort_t* WoT  = (ushort_t*)(ws + off); off += (size_t)1024 * 2048 / 2;
  // time-disjoint aliases (see table above)
  float*    U    = ws + qkv_off;                           // 6.29M fl
  ushort_t* SinT = (ushort_t*)(ws + qkv_off + 6291456);    // 3.15M fl
  ushort_t* g16  = (ushort_t*)(ws + q16_off);              // 8.39M fl over q16+kTp
  ushort_t* ob   = (ushort_t*)(ws + vTp_off);              // 8.39M fl over vTp

  dim3 thr(256);
  conv_to_bf16<<<M_ * HID_ / 1024, thr, 0, stream>>>(x, xb);
  transp_bf16<<<dim3(32, 32), thr, 0, stream>>>(Wq, WqT, 1024, 1024);
  transp_bf16<<<dim3(32, 32), thr, 0, stream>>>(Wk, WkT, 1024, 1024);
  transp_bf16<<<dim3(64, 32), thr, 0, stream>>>(Wv, WvT, 1024, 2048);
  transp_bf16<<<dim3(64, 32), thr, 0, stream>>>(Wg, WgT, 1024, 2048);
  transp_bf16<<<dim3(32, 64), thr, 0, stream>>>(Wo, WoT, 2048, 1024);

  // fused q|k|v projection: BT = [WqT ; WkT ; WvT] (contiguous), bf16 out
  gemm_mfma<true><<<dim3(32, 64), thr, 0, stream>>>(xb, WqT, qkv16, 4096, 1024);
  gk_kernel<<<M_, thr, 0, stream>>>(x, Wgk, bgk, gk);
  cumsum_kernel<<<16, 64, 0, stream>>>(gk, gc);
  a_mfma<<<16 * NC_, thr, 0, stream>>>(qkv16, gc, ab16);
  pack_q16<<<M_ * 1024 / 2048, thr, 0, stream>>>(qkv16, gc, q16);
  pack_kT<<<16 * NC_, thr, 0, stream>>>(qkv16, gc, kTp);
  pack_vT<<<16 * NC_ * 2, thr, 0, stream>>>(qkv16, vTp);
  scan_mfma<<<dim3(16, 8, NSEG_), thr, 0, stream>>>(q16, kTp, vTp, ab16, gc, o, U);
  combine_kernel<<<dim3(16, 32), thr, 0, stream>>>(U, gc, SinT);
  correct_kernel<<<dim3(16, 32, NSEG_ - 1), thr, 0, stream>>>(q16, SinT, gc, o);
  gemm_mfma<true><<<dim3(16, 64), thr, 0, stream>>>(xb, WgT, g16, 2048, 1024);
  normgate_kernel<<<M_ * NH_, thr, 0, stream>>>(o, g16, gw, ob);
  gemm_mfma<false><<<dim3(8, 64), thr, 0, stream>>>(ob, WoT, (float*)d_out, 1024, 2048);
}